// Round 5
// baseline (168.904 us; speedup 1.0000x reference)
//
#include <hip/hip_runtime.h>
#include <hip/hip_bf16.h>
#include <stdint.h>

// ---------------- problem constants ----------------
#define PDIM   1024
#define HEADS  16
#define DHEAD  64
#define BATCH  2
#define SEQ    2048
#define ROWS   (BATCH*SEQ)     // 4096
#define NBH    (BATCH*HEADS)   // 32

typedef __attribute__((ext_vector_type(8))) short s8v;    // 8 x bf16 (4 VGPR)
typedef __attribute__((ext_vector_type(4))) float f32x4;  // MFMA accumulator
typedef unsigned short ushort_t;
typedef unsigned int   uint32;

// Q pre-scale: DIM_HEAD^-0.5 * log2(e)  (softmax done in exp2 units)
#define QSCALE 0.18033688011112042f
// fixed softmax bias (log2 units): p = exp2(s - MFIX); cancels in num/denom
#define MFIX 12.0f

// ---------------- helpers ----------------
__device__ __forceinline__ ushort_t f2bf(float x){
  union { float f; uint32 u; } v; v.f = x;
  uint32 r = v.u + 0x7FFFu + ((v.u >> 16) & 1u);   // RTN-even
  return (ushort_t)(r >> 16);
}
__device__ __forceinline__ float bf2f(ushort_t h){
  union { float f; uint32 u; } v; v.u = ((uint32)h) << 16;
  return v.f;
}

typedef const __attribute__((address_space(1))) void* gas_ptr;
typedef __attribute__((address_space(3))) void*       las_ptr;
__device__ __forceinline__ void g2l16(const void* g, void* l){
  // dest = wave-uniform LDS base; HW adds lane*16
  __builtin_amdgcn_global_load_lds((gas_ptr)g, (las_ptr)l, 16, 0, 0);
}

// ---------------- fp32 -> bf16 convert (hi only) ----------------
__global__ __launch_bounds__(256) void k_cvt(const float* __restrict__ src,
                                             ushort_t* __restrict__ dst, int n4){
  int i = blockIdx.x * 256 + threadIdx.x;
  if (i >= n4) return;
  float4 v = reinterpret_cast<const float4*>(src)[i];
  reinterpret_cast<ushort4*>(dst)[i] =
      make_ushort4(f2bf(v.x), f2bf(v.y), f2bf(v.z), f2bf(v.w));
}

// ---------------- transpose + split: src[R][C] f32 -> dst[C][R] bf16 (lo optional) ----------------
__global__ __launch_bounds__(256) void k_tsplit(const float* __restrict__ src, int R, int C,
                                                ushort_t* __restrict__ dh,
                                                ushort_t* __restrict__ dl){
  __shared__ float tile[64][65];
  int cb = blockIdx.x * 64, rb = blockIdx.y * 64;
  int t = threadIdx.x;
  int lw = t >> 6;      // wave id 0..3
  int lc = t & 63;      // lane 0..63
#pragma unroll
  for (int i = 0; i < 16; i++){
    int r = i * 4 + lw;
    tile[r][lc] = src[(size_t)(rb + r) * C + cb + lc];
  }
  __syncthreads();
#pragma unroll
  for (int i = 0; i < 16; i++){
    int c = i * 4 + lw;
    float v = tile[lc][c];
    ushort_t hh = f2bf(v);
    size_t o = (size_t)(cb + c) * R + rb + lc;
    dh[o] = hh;
    if (dl) dl[o] = f2bf(v - bf2f(hh));
  }
}

// ---------------- GEMM core (128x128 tile, BK=64, 4 waves, dbuf + swizzle) ----------------
#define GBM 128
#define GBN 128
#define GBK 64

// ---------------- QKV projection GEMM, fused per-head epilogue ----------------
// A = Xh [4096][1024] bf16, B parts: Wqt_h then Wqt_l (each [3072][1024] bf16).
// C = Xh*(Wh + Wl)^T accumulated over K'=2048 (2-term split precision).
// Epilogue writes directly: Qh/Ql [bh][n][64] (scaled), Kh [bh][n][64], Vth [bh][d][SEQ].
// LDS: double-buffered, source-side XOR swizzle; counted vmcnt(8) + raw barriers.
// Grid: 768 blocks, XCD-chunked (each XCD owns 4 M-panels x 24 N-panels).
__global__ __launch_bounds__(256, 2) void k_gemm_qkv(
    const ushort_t* __restrict__ Xh,
    const ushort_t* __restrict__ Wqt_h, const ushort_t* __restrict__ Wqt_l,
    ushort_t* __restrict__ Qh, ushort_t* __restrict__ Ql,
    ushort_t* __restrict__ Kh, ushort_t* __restrict__ Vth){
  __shared__ __align__(16) ushort_t Asm[2][GBM * GBK];
  __shared__ __align__(16) ushort_t Bsm[2][GBM * GBK];
  const int tid  = threadIdx.x;
  const int wave = tid >> 6, lane = tid & 63;
  const int lid = blockIdx.x;                 // 0..767
  const int xcd = lid & 7, g = lid >> 3;      // 96 blocks per XCD
  const int mb = (xcd * 4 + g / 24) * GBM;    // 4 consecutive M-panels per XCD
  const int nb = (g % 24) * GBN;
  const int wr = wave >> 1, wc = wave & 1;
  const int l15 = lane & 15, l4 = lane >> 4;
  const int rsub = lane >> 3;
  const int schunk = ((lane & 7) ^ rsub) * 8;  // source-swizzled chunk
  f32x4 acc[4][4] = {};

  auto stage = [&](int buf, int kb){
    int part = kb >> 4;
    int k0   = (kb & 15) * GBK;
    const ushort_t* Bs = part ? Wqt_l : Wqt_h;
#pragma unroll
    for (int i = 0; i < 4; i++){
      int row = (i * 4 + wave) * 8 + rsub;
      g2l16(Xh + (size_t)(mb + row) * 1024 + k0 + schunk, &Asm[buf][(i * 4 + wave) * 512]);
      g2l16(Bs + (size_t)(nb + row) * 1024 + k0 + schunk, &Bsm[buf][(i * 4 + wave) * 512]);
    }
  };

  stage(0, 0);

  for (int kb = 0; kb < 32; kb++){
    const int cur = kb & 1;
    if (kb < 31){
      stage(cur ^ 1, kb + 1);                          // next tile's 8 loads in flight
      asm volatile("s_waitcnt vmcnt(8)" ::: "memory"); // current tile's 8 have landed
    } else {
      asm volatile("s_waitcnt vmcnt(0)" ::: "memory");
    }
    __builtin_amdgcn_s_barrier();
    __builtin_amdgcn_s_setprio(1);
#pragma unroll
    for (int ks = 0; ks < 2; ks++){
      s8v af[4], bfr[4];
#pragma unroll
      for (int f = 0; f < 4; f++){
        int ch = (((ks * 4 + l4) ^ (l15 & 7)) << 3);
        af[f]  = *reinterpret_cast<const s8v*>(&Asm[cur][(wr * 64 + f * 16 + l15) * 64 + ch]);
        bfr[f] = *reinterpret_cast<const s8v*>(&Bsm[cur][(wc * 64 + f * 16 + l15) * 64 + ch]);
      }
#pragma unroll
      for (int fr = 0; fr < 4; fr++)
#pragma unroll
        for (int fc = 0; fc < 4; fc++)
          acc[fr][fc] = __builtin_amdgcn_mfma_f32_16x16x32_bf16(af[fr], bfr[fc], acc[fr][fc], 0, 0, 0);
    }
    __builtin_amdgcn_s_setprio(0);
    __builtin_amdgcn_s_barrier();   // protect cur buffer before next stage overwrites
  }

  // fused epilogue: cols [nb,nb+128) all in one part (1024 % 128 == 0)
  const int pnum = nb >> 10;
#pragma unroll
  for (int fr = 0; fr < 4; fr++){
    int row  = mb + wr * 64 + fr * 16 + l4 * 4;   // +r, all 4 in same batch
    int b    = row >> 11;
    int nseq = row & 2047;
#pragma unroll
    for (int fc = 0; fc < 4; fc++){
      int col = nb + wc * 64 + fc * 16 + l15;
      int rem = col & 1023;
      int h = rem >> 6, d = rem & 63;
      int bh = b * 16 + h;
      if (pnum == 0){          // Q: scale, split hi/lo
        size_t base = ((size_t)bh * SEQ + nseq) * 64 + d;
#pragma unroll
        for (int r = 0; r < 4; r++){
          float q = acc[fr][fc][r] * QSCALE;
          ushort_t qh_ = f2bf(q);
          Qh[base + (size_t)r * 64] = qh_;
          Ql[base + (size_t)r * 64] = f2bf(q - bf2f(qh_));
        }
      } else if (pnum == 1){   // K: hi only
        size_t base = ((size_t)bh * SEQ + nseq) * 64 + d;
#pragma unroll
        for (int r = 0; r < 4; r++)
          Kh[base + (size_t)r * 64] = f2bf(acc[fr][fc][r]);
      } else {                 // V: transposed [bh][d][SEQ], 4 consecutive n
        size_t base = ((size_t)bh * 64 + d) * SEQ + nseq;
        *reinterpret_cast<ushort4*>(&Vth[base]) =
            make_ushort4(f2bf(acc[fr][fc][0]), f2bf(acc[fr][fc][1]),
                         f2bf(acc[fr][fc][2]), f2bf(acc[fr][fc][3]));
      }
    }
  }
}

// ---------------- out-projection GEMM (plain bf16, 1-term, dbuf + swizzle) ----------------
// Grid: 256 blocks, XCD-chunked (each XCD owns 4 M-panels x 8 N-panels).
__global__ __launch_bounds__(256, 2) void k_gemm_out(
    const ushort_t* __restrict__ Ah, const ushort_t* __restrict__ Bth,
    float* __restrict__ C, const float* __restrict__ bias){
  __shared__ __align__(16) ushort_t Asm[2][GBM * GBK];
  __shared__ __align__(16) ushort_t Bsm[2][GBM * GBK];
  const int tid  = threadIdx.x;
  const int wave = tid >> 6, lane = tid & 63;
  const int lid = blockIdx.x;                 // 0..255
  const int xcd = lid & 7, g = lid >> 3;      // 32 blocks per XCD
  const int mb = (xcd * 4 + (g >> 3)) * GBM;
  const int nb = (g & 7) * GBN;
  const int wr = wave >> 1, wc = wave & 1;
  const int l15 = lane & 15, l4 = lane >> 4;
  const int rsub = lane >> 3;
  const int schunk = ((lane & 7) ^ rsub) * 8;
  f32x4 acc[4][4] = {};

  auto stage = [&](int buf, int kb){
    int k0 = kb * GBK;
#pragma unroll
    for (int i = 0; i < 4; i++){
      int row = (i * 4 + wave) * 8 + rsub;
      g2l16(Ah  + (size_t)(mb + row) * 1024 + k0 + schunk, &Asm[buf][(i * 4 + wave) * 512]);
      g2l16(Bth + (size_t)(nb + row) * 1024 + k0 + schunk, &Bsm[buf][(i * 4 + wave) * 512]);
    }
  };

  stage(0, 0);

  for (int kb = 0; kb < 16; kb++){
    const int cur = kb & 1;
    if (kb < 15){
      stage(cur ^ 1, kb + 1);
      asm volatile("s_waitcnt vmcnt(8)" ::: "memory");
    } else {
      asm volatile("s_waitcnt vmcnt(0)" ::: "memory");
    }
    __builtin_amdgcn_s_barrier();
    __builtin_amdgcn_s_setprio(1);
#pragma unroll
    for (int ks = 0; ks < 2; ks++){
      s8v af[4], bfr[4];
#pragma unroll
      for (int f = 0; f < 4; f++){
        int ch = (((ks * 4 + l4) ^ (l15 & 7)) << 3);
        af[f]  = *reinterpret_cast<const s8v*>(&Asm[cur][(wr * 64 + f * 16 + l15) * 64 + ch]);
        bfr[f] = *reinterpret_cast<const s8v*>(&Bsm[cur][(wc * 64 + f * 16 + l15) * 64 + ch]);
      }
#pragma unroll
      for (int fr = 0; fr < 4; fr++)
#pragma unroll
        for (int fc = 0; fc < 4; fc++)
          acc[fr][fc] = __builtin_amdgcn_mfma_f32_16x16x32_bf16(af[fr], bfr[fc], acc[fr][fc], 0, 0, 0);
    }
    __builtin_amdgcn_s_setprio(0);
    __builtin_amdgcn_s_barrier();
  }
#pragma unroll
  for (int fr = 0; fr < 4; fr++){
    int row = mb + wr * 64 + fr * 16 + l4 * 4;
#pragma unroll
    for (int fc = 0; fc < 4; fc++){
      int col = nb + wc * 64 + fc * 16 + l15;
      float bv = bias[col];
#pragma unroll
      for (int r = 0; r < 4; r++)
        C[(size_t)(row + r) * 1024 + col] = acc[fr][fc][r] + bv;
    }
  }
}

// ---------------- flash attention (fixed-max, double-buffered, QBLK=128) ----------------
// 512 blocks (XCD-remapped) = 2/CU exactly; 4 waves x 32 q-rows. KV tiles of 64.
// QK^T: 2-term ((Qh+Ql)*Kh) in log2 units. Softmax: fixed bias MFIX (no online max).
// PV: 1-term. K/V double-buffered, counted vmcnt(4) + raw barriers.
__global__ __launch_bounds__(256, 2) void k_flash(
    const ushort_t* __restrict__ Qh, const ushort_t* __restrict__ Ql,
    const ushort_t* __restrict__ Kh, const ushort_t* __restrict__ Vth,
    ushort_t* __restrict__ Ah){
  __shared__ __align__(16) ushort_t KhS[2][64 * 64];
  __shared__ __align__(16) ushort_t VhS[2][64 * 64];
  __shared__ __align__(16) ushort_t PhS[128 * 72];
  const int lid = blockIdx.x;             // 0..511
  const int xcd = lid & 7, g = lid >> 3;  // 8 XCDs x 64 blocks
  const int bh = xcd * 4 + (g & 3);       // each XCD owns 4 heads
  const int qb = (g >> 2) * 128;
  const int tid = threadIdx.x, wave = tid >> 6, lane = tid & 63;
  const int l15 = lane & 15, l4 = lane >> 4;
  const int b = bh >> 4, h = bh & 15;
  const size_t hbase = (size_t)bh * SEQ * 64;
  const int rsub = lane >> 3;
  const int schunk = ((lane & 7) ^ rsub) * 8;

  // Q fragments (hi/lo), 32 q-rows per wave
  s8v qhf[2][2], qlf[2][2];
#pragma unroll
  for (int fr = 0; fr < 2; fr++)
#pragma unroll
    for (int ks = 0; ks < 2; ks++){
      size_t off = hbase + (size_t)(qb + wave * 32 + fr * 16 + l15) * 64 + ks * 32 + l4 * 8;
      qhf[fr][ks] = *reinterpret_cast<const s8v*>(&Qh[off]);
      qlf[fr][ks] = *reinterpret_cast<const s8v*>(&Ql[off]);
    }

  f32x4 o[2][4] = {};
  float lsum[2][4] = {};

  auto stage = [&](int buf, int kt){
    int kvb = kt * 64;
#pragma unroll
    for (int i = 0; i < 2; i++){
      int row = (i * 4 + wave) * 8 + rsub;
      g2l16(Kh  + hbase + (size_t)(kvb + row) * 64 + schunk, &KhS[buf][(i * 4 + wave) * 512]);
      g2l16(Vth + ((size_t)bh * 64 + row) * SEQ + kvb + schunk, &VhS[buf][(i * 4 + wave) * 512]);
    }
  };

  stage(0, 0);

  for (int kt = 0; kt < 32; kt++){
    const int cur = kt & 1;
    if (kt < 31){
      stage(cur ^ 1, kt + 1);                          // next tile's 4 loads in flight
      asm volatile("s_waitcnt vmcnt(4)" ::: "memory"); // current tile's 4 have landed
    } else {
      asm volatile("s_waitcnt vmcnt(0)" ::: "memory");
    }
    __builtin_amdgcn_s_barrier();

    // S = Q K^T (2-term), swizzled LDS reads; kh shared across both fr sub-tiles
    f32x4 s[2][4] = {};
    __builtin_amdgcn_s_setprio(1);
#pragma unroll
    for (int ks = 0; ks < 2; ks++)
#pragma unroll
      for (int fc = 0; fc < 4; fc++){
        int rK = fc * 16 + l15;
        int ch = ((ks * 4 + l4) ^ (rK & 7)) << 3;
        s8v kh = *reinterpret_cast<const s8v*>(&KhS[cur][rK * 64 + ch]);
#pragma unroll
        for (int fr = 0; fr < 2; fr++){
          s[fr][fc] = __builtin_amdgcn_mfma_f32_16x16x32_bf16(qhf[fr][ks], kh, s[fr][fc], 0, 0, 0);
          s[fr][fc] = __builtin_amdgcn_mfma_f32_16x16x32_bf16(qlf[fr][ks], kh, s[fr][fc], 0, 0, 0);
        }
      }
    __builtin_amdgcn_s_setprio(0);

    // fixed-max softmax: p = exp2(s - MFIX); per-lane lsum; write P_hi to LDS
#pragma unroll
    for (int fr = 0; fr < 2; fr++)
#pragma unroll
      for (int fc = 0; fc < 4; fc++)
#pragma unroll
        for (int r = 0; r < 4; r++){
          float p = __builtin_amdgcn_exp2f(s[fr][fc][r] - MFIX);
          lsum[fr][r] += p;
          int prow = wave * 32 + fr * 16 + l4 * 4 + r;
          int col  = (fc * 16 + l15) ^ (((prow >> 2) & 3) << 3);
          PhS[prow * 72 + col] = f2bf(p);
        }

    // O += P_hi V_hi ; vh shared across both fr sub-tiles
    __builtin_amdgcn_s_setprio(1);
#pragma unroll
    for (int c = 0; c < 2; c++){
      s8v pa[2];
#pragma unroll
      for (int fr = 0; fr < 2; fr++){
        int prow = wave * 32 + fr * 16 + l15;
        int u = (prow >> 2) & 3;
        pa[fr] = *reinterpret_cast<const s8v*>(&PhS[prow * 72 + (((c * 4 + l4) ^ u) << 3)]);
      }
#pragma unroll
      for (int fd = 0; fd < 4; fd++){
        int rV = fd * 16 + l15;
        int ch = ((c * 4 + l4) ^ (rV & 7)) << 3;
        s8v vh = *reinterpret_cast<const s8v*>(&VhS[cur][rV * 64 + ch]);
        o[0][fd] = __builtin_amdgcn_mfma_f32_16x16x32_bf16(pa[0], vh, o[0][fd], 0, 0, 0);
        o[1][fd] = __builtin_amdgcn_mfma_f32_16x16x32_bf16(pa[1], vh, o[1][fd], 0, 0, 0);
      }
    }
    __builtin_amdgcn_s_setprio(0);
    __builtin_amdgcn_s_barrier();   // protect cur buffers before next stage overwrites
  }

  // epilogue: reduce lsum across the 16-lane row group (once), write bf16 Ah
#pragma unroll
  for (int fr = 0; fr < 2; fr++)
#pragma unroll
    for (int msk = 1; msk < 16; msk <<= 1)
#pragma unroll
      for (int r = 0; r < 4; r++)
        lsum[fr][r] += __shfl_xor(lsum[fr][r], msk);
#pragma unroll
  for (int fr = 0; fr < 2; fr++)
#pragma unroll
    for (int r = 0; r < 4; r++){
      float inv = 1.f / lsum[fr][r];
      int n = qb + wave * 32 + fr * 16 + l4 * 4 + r;
      size_t rowbase = (size_t)(b * SEQ + n) * 1024 + h * 64;
#pragma unroll
      for (int fd = 0; fd < 4; fd++)
        Ah[rowbase + fd * 16 + l15] = f2bf(o[fr][fd][r] * inv);
    }
}

// ---------------- host launch ----------------
extern "C" void kernel_launch(void* const* d_in, const int* in_sizes, int n_in,
                              void* d_out, int out_size, void* d_ws, size_t ws_size,
                              hipStream_t stream){
  const float* x     = (const float*)d_in[0];
  const float* w_qkv = (const float*)d_in[1];
  const float* w_out = (const float*)d_in[2];
  const float* b_out = (const float*)d_in[3];
  float* out = (float*)d_out;
  char* ws = (char*)d_ws;

  ushort_t* Xh    = (ushort_t*)(ws);                      //  8 MB
  ushort_t* Wqt_h = (ushort_t*)(ws + 8388608);            //  6 MB
  ushort_t* Wqt_l = (ushort_t*)(ws + 14680064);           //  6 MB
  ushort_t* Wot_h = (ushort_t*)(ws + 20971520);           //  2 MB
  ushort_t* Qh    = (ushort_t*)(ws + 23068672);           //  8 MB
  ushort_t* Ql    = (ushort_t*)(ws + 31457280);           //  8 MB
  ushort_t* Kh    = (ushort_t*)(ws + 39845888);           //  8 MB
  ushort_t* Vth   = (ushort_t*)(ws + 48234496);           //  8 MB
  ushort_t* Ah    = (ushort_t*)(ws + 56623104);           //  8 MB

  // 1. x -> Xh (bf16)
  k_cvt<<<4096, 256, 0, stream>>>(x, Xh, ROWS * PDIM / 4);
  // 2. w_qkv [1024][3072] -> Wqt [3072][1024] hi/lo
  k_tsplit<<<dim3(48, 16), 256, 0, stream>>>(w_qkv, 1024, 3072, Wqt_h, Wqt_l);
  // 3. w_out [1024][1024] -> Wot [1024][1024] hi only
  k_tsplit<<<dim3(16, 16), 256, 0, stream>>>(w_out, 1024, 1024, Wot_h, nullptr);
  // 4. QKV projection (2-term) with fused per-head epilogue
  k_gemm_qkv<<<768, 256, 0, stream>>>(Xh, Wqt_h, Wqt_l, Qh, Ql, Kh, Vth);
  // 5. attention -> Ah (bf16)
  k_flash<<<512, 256, 0, stream>>>(Qh, Ql, Kh, Vth, Ah);
  // 6. out = Ah @ Wot + b_out
  k_gemm_out<<<256, 256, 0, stream>>>(Ah, Wot_h, out, b_out);
}

// Round 6
// 136.981 us; speedup vs baseline: 1.2330x; 1.2330x over previous
//
#include <hip/hip_runtime.h>
#include <hip/hip_bf16.h>
#include <stdint.h>

// ---------------- problem constants ----------------
#define PDIM   1024
#define HEADS  16
#define DHEAD  64
#define BATCH  2
#define SEQ    2048
#define ROWS   (BATCH*SEQ)     // 4096
#define NBH    (BATCH*HEADS)   // 32

typedef __attribute__((ext_vector_type(8))) short s8v;    // 8 x bf16 (4 VGPR)
typedef __attribute__((ext_vector_type(4))) float f32x4;  // MFMA accumulator
typedef unsigned short ushort_t;
typedef unsigned int   uint32;

// Q pre-scale: DIM_HEAD^-0.5 * log2(e)  (softmax done in exp2 units)
#define QSCALE 0.18033688011112042f
// fixed softmax bias (log2 units): p = exp2(s - MFIX); cancels in num/denom
#define MFIX 12.0f

// ---------------- helpers ----------------
__device__ __forceinline__ ushort_t f2bf(float x){
  union { float f; uint32 u; } v; v.f = x;
  uint32 r = v.u + 0x7FFFu + ((v.u >> 16) & 1u);   // RTN-even
  return (ushort_t)(r >> 16);
}
__device__ __forceinline__ float bf2f(ushort_t h){
  union { float f; uint32 u; } v; v.u = ((uint32)h) << 16;
  return v.f;
}

typedef const __attribute__((address_space(1))) void* gas_ptr;
typedef __attribute__((address_space(3))) void*       las_ptr;
__device__ __forceinline__ void g2l16(const void* g, void* l){
  // dest = wave-uniform LDS base; HW adds lane*16
  __builtin_amdgcn_global_load_lds((gas_ptr)g, (las_ptr)l, 16, 0, 0);
}

// ---------------- fp32 -> bf16 convert (hi only) ----------------
__global__ __launch_bounds__(256) void k_cvt(const float* __restrict__ src,
                                             ushort_t* __restrict__ dst, int n4){
  int i = blockIdx.x * 256 + threadIdx.x;
  if (i >= n4) return;
  float4 v = reinterpret_cast<const float4*>(src)[i];
  reinterpret_cast<ushort4*>(dst)[i] =
      make_ushort4(f2bf(v.x), f2bf(v.y), f2bf(v.z), f2bf(v.w));
}

// ---------------- transpose: src[R][C] f32 -> dst[C][R] bf16 (hi only) ----------------
__global__ __launch_bounds__(256) void k_tcvt(const float* __restrict__ src, int R, int C,
                                              ushort_t* __restrict__ dh){
  __shared__ float tile[64][65];
  int cb = blockIdx.x * 64, rb = blockIdx.y * 64;
  int t = threadIdx.x;
  int lw = t >> 6;      // wave id 0..3
  int lc = t & 63;      // lane 0..63
#pragma unroll
  for (int i = 0; i < 16; i++){
    int r = i * 4 + lw;
    tile[r][lc] = src[(size_t)(rb + r) * C + cb + lc];
  }
  __syncthreads();
#pragma unroll
  for (int i = 0; i < 16; i++){
    int c = i * 4 + lw;
    dh[(size_t)(cb + c) * R + rb + lc] = f2bf(tile[lc][c]);
  }
}

// ---------------- GEMM core (128x128 tile, BK=64, 4 waves, dbuf + swizzle) ----------------
#define GBM 128
#define GBN 128
#define GBK 64

// ---------------- QKV projection GEMM, fused per-head epilogue ----------------
// A = Xh [4096][1024] bf16, B = Wqt_h [3072][1024] bf16 (1-term).
// Epilogue writes directly: Qh/Ql [bh][n][64] (scaled), Kh [bh][n][64], Vth [bh][d][SEQ].
// LDS: double-buffered, source-side XOR swizzle; counted vmcnt(8) + raw barriers.
// Grid: dim3(24, 32) — default interleaved XCD dispatch (chunking measured WORSE, r5).
__global__ __launch_bounds__(256, 2) void k_gemm_qkv(
    const ushort_t* __restrict__ Xh, const ushort_t* __restrict__ Wqt_h,
    ushort_t* __restrict__ Qh, ushort_t* __restrict__ Ql,
    ushort_t* __restrict__ Kh, ushort_t* __restrict__ Vth){
  __shared__ __align__(16) ushort_t Asm[2][GBM * GBK];
  __shared__ __align__(16) ushort_t Bsm[2][GBM * GBK];
  const int tid  = threadIdx.x;
  const int wave = tid >> 6, lane = tid & 63;
  const int mb = blockIdx.y * GBM, nb = blockIdx.x * GBN;
  const int wr = wave >> 1, wc = wave & 1;
  const int l15 = lane & 15, l4 = lane >> 4;
  const int rsub = lane >> 3;
  const int schunk = ((lane & 7) ^ rsub) * 8;  // source-swizzled chunk
  f32x4 acc[4][4] = {};

  auto stage = [&](int buf, int kb){
    int k0 = kb * GBK;
#pragma unroll
    for (int i = 0; i < 4; i++){
      int row = (i * 4 + wave) * 8 + rsub;
      g2l16(Xh    + (size_t)(mb + row) * 1024 + k0 + schunk, &Asm[buf][(i * 4 + wave) * 512]);
      g2l16(Wqt_h + (size_t)(nb + row) * 1024 + k0 + schunk, &Bsm[buf][(i * 4 + wave) * 512]);
    }
  };

  stage(0, 0);

  for (int kb = 0; kb < 16; kb++){
    const int cur = kb & 1;
    if (kb < 15){
      stage(cur ^ 1, kb + 1);                          // next tile's 8 loads in flight
      asm volatile("s_waitcnt vmcnt(8)" ::: "memory"); // current tile's 8 have landed
    } else {
      asm volatile("s_waitcnt vmcnt(0)" ::: "memory");
    }
    __builtin_amdgcn_s_barrier();
    __builtin_amdgcn_s_setprio(1);
#pragma unroll
    for (int ks = 0; ks < 2; ks++){
      s8v af[4], bfr[4];
#pragma unroll
      for (int f = 0; f < 4; f++){
        int ch = (((ks * 4 + l4) ^ (l15 & 7)) << 3);
        af[f]  = *reinterpret_cast<const s8v*>(&Asm[cur][(wr * 64 + f * 16 + l15) * 64 + ch]);
        bfr[f] = *reinterpret_cast<const s8v*>(&Bsm[cur][(wc * 64 + f * 16 + l15) * 64 + ch]);
      }
#pragma unroll
      for (int fr = 0; fr < 4; fr++)
#pragma unroll
        for (int fc = 0; fc < 4; fc++)
          acc[fr][fc] = __builtin_amdgcn_mfma_f32_16x16x32_bf16(af[fr], bfr[fc], acc[fr][fc], 0, 0, 0);
    }
    __builtin_amdgcn_s_setprio(0);
    __builtin_amdgcn_s_barrier();   // protect cur buffer before next stage overwrites
  }

  // fused epilogue: cols [nb,nb+128) all in one part (1024 % 128 == 0)
  const int pnum = nb >> 10;
#pragma unroll
  for (int fr = 0; fr < 4; fr++){
    int row  = mb + wr * 64 + fr * 16 + l4 * 4;   // +r, all 4 in same batch
    int b    = row >> 11;
    int nseq = row & 2047;
#pragma unroll
    for (int fc = 0; fc < 4; fc++){
      int col = nb + wc * 64 + fc * 16 + l15;
      int rem = col & 1023;
      int h = rem >> 6, d = rem & 63;
      int bh = b * 16 + h;
      if (pnum == 0){          // Q: scale, split hi/lo
        size_t base = ((size_t)bh * SEQ + nseq) * 64 + d;
#pragma unroll
        for (int r = 0; r < 4; r++){
          float q = acc[fr][fc][r] * QSCALE;
          ushort_t qh_ = f2bf(q);
          Qh[base + (size_t)r * 64] = qh_;
          Ql[base + (size_t)r * 64] = f2bf(q - bf2f(qh_));
        }
      } else if (pnum == 1){   // K: hi only
        size_t base = ((size_t)bh * SEQ + nseq) * 64 + d;
#pragma unroll
        for (int r = 0; r < 4; r++)
          Kh[base + (size_t)r * 64] = f2bf(acc[fr][fc][r]);
      } else {                 // V: transposed [bh][d][SEQ], 4 consecutive n
        size_t base = ((size_t)bh * 64 + d) * SEQ + nseq;
        *reinterpret_cast<ushort4*>(&Vth[base]) =
            make_ushort4(f2bf(acc[fr][fc][0]), f2bf(acc[fr][fc][1]),
                         f2bf(acc[fr][fc][2]), f2bf(acc[fr][fc][3]));
      }
    }
  }
}

// ---------------- out-projection GEMM (plain bf16, 1-term, dbuf + swizzle) ----------------
// Grid: dim3(8, 32) — default interleaved dispatch.
__global__ __launch_bounds__(256, 2) void k_gemm_out(
    const ushort_t* __restrict__ Ah, const ushort_t* __restrict__ Bth,
    float* __restrict__ C, const float* __restrict__ bias){
  __shared__ __align__(16) ushort_t Asm[2][GBM * GBK];
  __shared__ __align__(16) ushort_t Bsm[2][GBM * GBK];
  const int tid  = threadIdx.x;
  const int wave = tid >> 6, lane = tid & 63;
  const int mb = blockIdx.y * GBM, nb = blockIdx.x * GBN;
  const int wr = wave >> 1, wc = wave & 1;
  const int l15 = lane & 15, l4 = lane >> 4;
  const int rsub = lane >> 3;
  const int schunk = ((lane & 7) ^ rsub) * 8;
  f32x4 acc[4][4] = {};

  auto stage = [&](int buf, int kb){
    int k0 = kb * GBK;
#pragma unroll
    for (int i = 0; i < 4; i++){
      int row = (i * 4 + wave) * 8 + rsub;
      g2l16(Ah  + (size_t)(mb + row) * 1024 + k0 + schunk, &Asm[buf][(i * 4 + wave) * 512]);
      g2l16(Bth + (size_t)(nb + row) * 1024 + k0 + schunk, &Bsm[buf][(i * 4 + wave) * 512]);
    }
  };

  stage(0, 0);

  for (int kb = 0; kb < 16; kb++){
    const int cur = kb & 1;
    if (kb < 15){
      stage(cur ^ 1, kb + 1);
      asm volatile("s_waitcnt vmcnt(8)" ::: "memory");
    } else {
      asm volatile("s_waitcnt vmcnt(0)" ::: "memory");
    }
    __builtin_amdgcn_s_barrier();
    __builtin_amdgcn_s_setprio(1);
#pragma unroll
    for (int ks = 0; ks < 2; ks++){
      s8v af[4], bfr[4];
#pragma unroll
      for (int f = 0; f < 4; f++){
        int ch = (((ks * 4 + l4) ^ (l15 & 7)) << 3);
        af[f]  = *reinterpret_cast<const s8v*>(&Asm[cur][(wr * 64 + f * 16 + l15) * 64 + ch]);
        bfr[f] = *reinterpret_cast<const s8v*>(&Bsm[cur][(wc * 64 + f * 16 + l15) * 64 + ch]);
      }
#pragma unroll
      for (int fr = 0; fr < 4; fr++)
#pragma unroll
        for (int fc = 0; fc < 4; fc++)
          acc[fr][fc] = __builtin_amdgcn_mfma_f32_16x16x32_bf16(af[fr], bfr[fc], acc[fr][fc], 0, 0, 0);
    }
    __builtin_amdgcn_s_setprio(0);
    __builtin_amdgcn_s_barrier();
  }
#pragma unroll
  for (int fr = 0; fr < 4; fr++){
    int row = mb + wr * 64 + fr * 16 + l4 * 4;
#pragma unroll
    for (int fc = 0; fc < 4; fc++){
      int col = nb + wc * 64 + fc * 16 + l15;
      float bv = bias[col];
#pragma unroll
      for (int r = 0; r < 4; r++)
        C[(size_t)(row + r) * 1024 + col] = acc[fr][fc][r] + bv;
    }
  }
}

// ---------------- flash attention (fixed-max, double-buffered, QBLK=128) ----------------
// 512 blocks (XCD-remapped) = 2/CU exactly; 4 waves x 32 q-rows. KV tiles of 64.
// QK^T: 2-term ((Qh+Ql)*Kh) in log2 units. Softmax: fixed bias MFIX (no online max).
// PV: 1-term. K/V double-buffered, counted vmcnt(4) + raw barriers.
__global__ __launch_bounds__(256, 2) void k_flash(
    const ushort_t* __restrict__ Qh, const ushort_t* __restrict__ Ql,
    const ushort_t* __restrict__ Kh, const ushort_t* __restrict__ Vth,
    ushort_t* __restrict__ Ah){
  __shared__ __align__(16) ushort_t KhS[2][64 * 64];
  __shared__ __align__(16) ushort_t VhS[2][64 * 64];
  __shared__ __align__(16) ushort_t PhS[128 * 72];
  const int lid = blockIdx.x;             // 0..511
  const int xcd = lid & 7, g = lid >> 3;  // 8 XCDs x 64 blocks
  const int bh = xcd * 4 + (g & 3);       // each XCD owns 4 heads
  const int qb = (g >> 2) * 128;
  const int tid = threadIdx.x, wave = tid >> 6, lane = tid & 63;
  const int l15 = lane & 15, l4 = lane >> 4;
  const int b = bh >> 4, h = bh & 15;
  const size_t hbase = (size_t)bh * SEQ * 64;
  const int rsub = lane >> 3;
  const int schunk = ((lane & 7) ^ rsub) * 8;

  // Q fragments (hi/lo), 32 q-rows per wave
  s8v qhf[2][2], qlf[2][2];
#pragma unroll
  for (int fr = 0; fr < 2; fr++)
#pragma unroll
    for (int ks = 0; ks < 2; ks++){
      size_t off = hbase + (size_t)(qb + wave * 32 + fr * 16 + l15) * 64 + ks * 32 + l4 * 8;
      qhf[fr][ks] = *reinterpret_cast<const s8v*>(&Qh[off]);
      qlf[fr][ks] = *reinterpret_cast<const s8v*>(&Ql[off]);
    }

  f32x4 o[2][4] = {};
  float lsum[2][4] = {};

  auto stage = [&](int buf, int kt){
    int kvb = kt * 64;
#pragma unroll
    for (int i = 0; i < 2; i++){
      int row = (i * 4 + wave) * 8 + rsub;
      g2l16(Kh  + hbase + (size_t)(kvb + row) * 64 + schunk, &KhS[buf][(i * 4 + wave) * 512]);
      g2l16(Vth + ((size_t)bh * 64 + row) * SEQ + kvb + schunk, &VhS[buf][(i * 4 + wave) * 512]);
    }
  };

  stage(0, 0);

  for (int kt = 0; kt < 32; kt++){
    const int cur = kt & 1;
    if (kt < 31){
      stage(cur ^ 1, kt + 1);                          // next tile's 4 loads in flight
      asm volatile("s_waitcnt vmcnt(4)" ::: "memory"); // current tile's 4 have landed
    } else {
      asm volatile("s_waitcnt vmcnt(0)" ::: "memory");
    }
    __builtin_amdgcn_s_barrier();

    // S = Q K^T (2-term), swizzled LDS reads; kh shared across both fr sub-tiles
    f32x4 s[2][4] = {};
    __builtin_amdgcn_s_setprio(1);
#pragma unroll
    for (int ks = 0; ks < 2; ks++)
#pragma unroll
      for (int fc = 0; fc < 4; fc++){
        int rK = fc * 16 + l15;
        int ch = ((ks * 4 + l4) ^ (rK & 7)) << 3;
        s8v kh = *reinterpret_cast<const s8v*>(&KhS[cur][rK * 64 + ch]);
#pragma unroll
        for (int fr = 0; fr < 2; fr++){
          s[fr][fc] = __builtin_amdgcn_mfma_f32_16x16x32_bf16(qhf[fr][ks], kh, s[fr][fc], 0, 0, 0);
          s[fr][fc] = __builtin_amdgcn_mfma_f32_16x16x32_bf16(qlf[fr][ks], kh, s[fr][fc], 0, 0, 0);
        }
      }
    __builtin_amdgcn_s_setprio(0);

    // fixed-max softmax: p = exp2(s - MFIX); per-lane lsum; write P_hi to LDS
#pragma unroll
    for (int fr = 0; fr < 2; fr++)
#pragma unroll
      for (int fc = 0; fc < 4; fc++)
#pragma unroll
        for (int r = 0; r < 4; r++){
          float p = __builtin_amdgcn_exp2f(s[fr][fc][r] - MFIX);
          lsum[fr][r] += p;
          int prow = wave * 32 + fr * 16 + l4 * 4 + r;
          int col  = (fc * 16 + l15) ^ (((prow >> 2) & 3) << 3);
          PhS[prow * 72 + col] = f2bf(p);
        }

    // O += P_hi V_hi ; vh shared across both fr sub-tiles
    __builtin_amdgcn_s_setprio(1);
#pragma unroll
    for (int c = 0; c < 2; c++){
      s8v pa[2];
#pragma unroll
      for (int fr = 0; fr < 2; fr++){
        int prow = wave * 32 + fr * 16 + l15;
        int u = (prow >> 2) & 3;
        pa[fr] = *reinterpret_cast<const s8v*>(&PhS[prow * 72 + (((c * 4 + l4) ^ u) << 3)]);
      }
#pragma unroll
      for (int fd = 0; fd < 4; fd++){
        int rV = fd * 16 + l15;
        int ch = ((c * 4 + l4) ^ (rV & 7)) << 3;
        s8v vh = *reinterpret_cast<const s8v*>(&VhS[cur][rV * 64 + ch]);
        o[0][fd] = __builtin_amdgcn_mfma_f32_16x16x32_bf16(pa[0], vh, o[0][fd], 0, 0, 0);
        o[1][fd] = __builtin_amdgcn_mfma_f32_16x16x32_bf16(pa[1], vh, o[1][fd], 0, 0, 0);
      }
    }
    __builtin_amdgcn_s_setprio(0);
    __builtin_amdgcn_s_barrier();   // protect cur buffers before next stage overwrites
  }

  // epilogue: reduce lsum across the 16-lane row group (once), write bf16 Ah
#pragma unroll
  for (int fr = 0; fr < 2; fr++)
#pragma unroll
    for (int msk = 1; msk < 16; msk <<= 1)
#pragma unroll
      for (int r = 0; r < 4; r++)
        lsum[fr][r] += __shfl_xor(lsum[fr][r], msk);
#pragma unroll
  for (int fr = 0; fr < 2; fr++)
#pragma unroll
    for (int r = 0; r < 4; r++){
      float inv = 1.f / lsum[fr][r];
      int n = qb + wave * 32 + fr * 16 + l4 * 4 + r;
      size_t rowbase = (size_t)(b * SEQ + n) * 1024 + h * 64;
#pragma unroll
      for (int fd = 0; fd < 4; fd++)
        Ah[rowbase + fd * 16 + l15] = f2bf(o[fr][fd][r] * inv);
    }
}

// ---------------- host launch ----------------
extern "C" void kernel_launch(void* const* d_in, const int* in_sizes, int n_in,
                              void* d_out, int out_size, void* d_ws, size_t ws_size,
                              hipStream_t stream){
  const float* x     = (const float*)d_in[0];
  const float* w_qkv = (const float*)d_in[1];
  const float* w_out = (const float*)d_in[2];
  const float* b_out = (const float*)d_in[3];
  float* out = (float*)d_out;
  char* ws = (char*)d_ws;

  ushort_t* Xh    = (ushort_t*)(ws);                      //  8 MB
  ushort_t* Wqt_h = (ushort_t*)(ws + 8388608);            //  6 MB
  ushort_t* Wot_h = (ushort_t*)(ws + 14680064);           //  2 MB
  ushort_t* Qh    = (ushort_t*)(ws + 16777216);           //  8 MB
  ushort_t* Ql    = (ushort_t*)(ws + 25165824);           //  8 MB
  ushort_t* Kh    = (ushort_t*)(ws + 33554432);           //  8 MB
  ushort_t* Vth   = (ushort_t*)(ws + 41943040);           //  8 MB
  ushort_t* Ah    = (ushort_t*)(ws + 50331648);           //  8 MB

  // 1. x -> Xh (bf16)
  k_cvt<<<4096, 256, 0, stream>>>(x, Xh, ROWS * PDIM / 4);
  // 2. w_qkv [1024][3072] -> Wqt_h [3072][1024] (bf16 hi)
  k_tcvt<<<dim3(48, 16), 256, 0, stream>>>(w_qkv, 1024, 3072, Wqt_h);
  // 3. w_out [1024][1024] -> Wot_h [1024][1024] (bf16 hi)
  k_tcvt<<<dim3(16, 16), 256, 0, stream>>>(w_out, 1024, 1024, Wot_h);
  // 4. QKV projection (1-term) with fused per-head epilogue
  k_gemm_qkv<<<dim3(24, 32), 256, 0, stream>>>(Xh, Wqt_h, Qh, Ql, Kh, Vth);
  // 5. attention -> Ah (bf16)
  k_flash<<<512, 256, 0, stream>>>(Qh, Ql, Kh, Vth, Ah);
  // 6. out = Ah @ Wot + b_out
  k_gemm_out<<<dim3(8, 32), 256, 0, stream>>>(Ah, Wot_h, out, b_out);
}

// Round 7
// 133.628 us; speedup vs baseline: 1.2640x; 1.0251x over previous
//
#include <hip/hip_runtime.h>
#include <hip/hip_bf16.h>
#include <stdint.h>

// ---------------- problem constants ----------------
#define PDIM   1024
#define HEADS  16
#define DHEAD  64
#define BATCH  2
#define SEQ    2048
#define ROWS   (BATCH*SEQ)     // 4096
#define NBH    (BATCH*HEADS)   // 32

typedef __attribute__((ext_vector_type(8))) short s8v;    // 8 x bf16 (4 VGPR)
typedef __attribute__((ext_vector_type(4))) float f32x4;  // MFMA accumulator
typedef unsigned short ushort_t;
typedef unsigned int   uint32;

// Q pre-scale: DIM_HEAD^-0.5 * log2(e)  (softmax done in exp2 units)
#define QSCALE 0.18033688011112042f
// fixed softmax bias (log2 units): p = exp2(s - MFIX); cancels in num/denom
#define MFIX 12.0f

// ---------------- helpers ----------------
__device__ __forceinline__ ushort_t f2bf(float x){
  union { float f; uint32 u; } v; v.f = x;
  uint32 r = v.u + 0x7FFFu + ((v.u >> 16) & 1u);   // RTN-even
  return (ushort_t)(r >> 16);
}
__device__ __forceinline__ ushort_t f2bf_trunc(float x){
  union { float f; uint32 u; } v; v.f = x;
  return (ushort_t)(v.u >> 16);                    // truncate (P>=0, bias<=2^-9 rel)
}

typedef const __attribute__((address_space(1))) void* gas_ptr;
typedef __attribute__((address_space(3))) void*       las_ptr;
__device__ __forceinline__ void g2l16(const void* g, void* l){
  // dest = wave-uniform LDS base; HW adds lane*16
  __builtin_amdgcn_global_load_lds((gas_ptr)g, (las_ptr)l, 16, 0, 0);
}

// ---------------- fp32 -> bf16 convert (hi only) ----------------
__global__ __launch_bounds__(256) void k_cvt(const float* __restrict__ src,
                                             ushort_t* __restrict__ dst, int n4){
  int i = blockIdx.x * 256 + threadIdx.x;
  if (i >= n4) return;
  float4 v = reinterpret_cast<const float4*>(src)[i];
  reinterpret_cast<ushort4*>(dst)[i] =
      make_ushort4(f2bf(v.x), f2bf(v.y), f2bf(v.z), f2bf(v.w));
}

// ---------------- transpose: src[R][C] f32 -> dst[C][R] bf16 (hi only) ----------------
__global__ __launch_bounds__(256) void k_tcvt(const float* __restrict__ src, int R, int C,
                                              ushort_t* __restrict__ dh){
  __shared__ float tile[64][65];
  int cb = blockIdx.x * 64, rb = blockIdx.y * 64;
  int t = threadIdx.x;
  int lw = t >> 6;      // wave id 0..3
  int lc = t & 63;      // lane 0..63
#pragma unroll
  for (int i = 0; i < 16; i++){
    int r = i * 4 + lw;
    tile[r][lc] = src[(size_t)(rb + r) * C + cb + lc];
  }
  __syncthreads();
#pragma unroll
  for (int i = 0; i < 16; i++){
    int c = i * 4 + lw;
    dh[(size_t)(cb + c) * R + rb + lc] = f2bf(tile[lc][c]);
  }
}

// ---------------- GEMM core (128x128 tile, BK=64, 4 waves, dbuf + swizzle) ----------------
#define GBM 128
#define GBN 128
#define GBK 64

// ---------------- QKV projection GEMM, fused per-head epilogue ----------------
// A = Xh [4096][1024] bf16, B = Wqt_h [3072][1024] bf16 (1-term).
// Epilogue writes directly: Qh [bh][n][64] (scaled), Kh [bh][n][64], Vth [bh][d][SEQ].
__global__ __launch_bounds__(256, 2) void k_gemm_qkv(
    const ushort_t* __restrict__ Xh, const ushort_t* __restrict__ Wqt_h,
    ushort_t* __restrict__ Qh, ushort_t* __restrict__ Kh, ushort_t* __restrict__ Vth){
  __shared__ __align__(16) ushort_t Asm[2][GBM * GBK];
  __shared__ __align__(16) ushort_t Bsm[2][GBM * GBK];
  const int tid  = threadIdx.x;
  const int wave = tid >> 6, lane = tid & 63;
  const int mb = blockIdx.y * GBM, nb = blockIdx.x * GBN;
  const int wr = wave >> 1, wc = wave & 1;
  const int l15 = lane & 15, l4 = lane >> 4;
  const int rsub = lane >> 3;
  const int schunk = ((lane & 7) ^ rsub) * 8;  // source-swizzled chunk
  f32x4 acc[4][4] = {};

  auto stage = [&](int buf, int kb){
    int k0 = kb * GBK;
#pragma unroll
    for (int i = 0; i < 4; i++){
      int row = (i * 4 + wave) * 8 + rsub;
      g2l16(Xh    + (size_t)(mb + row) * 1024 + k0 + schunk, &Asm[buf][(i * 4 + wave) * 512]);
      g2l16(Wqt_h + (size_t)(nb + row) * 1024 + k0 + schunk, &Bsm[buf][(i * 4 + wave) * 512]);
    }
  };

  stage(0, 0);

  for (int kb = 0; kb < 16; kb++){
    const int cur = kb & 1;
    if (kb < 15){
      stage(cur ^ 1, kb + 1);                          // next tile's 8 loads in flight
      asm volatile("s_waitcnt vmcnt(8)" ::: "memory"); // current tile's 8 have landed
    } else {
      asm volatile("s_waitcnt vmcnt(0)" ::: "memory");
    }
    __builtin_amdgcn_s_barrier();
    __builtin_amdgcn_s_setprio(1);
#pragma unroll
    for (int ks = 0; ks < 2; ks++){
      s8v af[4], bfr[4];
#pragma unroll
      for (int f = 0; f < 4; f++){
        int ch = (((ks * 4 + l4) ^ (l15 & 7)) << 3);
        af[f]  = *reinterpret_cast<const s8v*>(&Asm[cur][(wr * 64 + f * 16 + l15) * 64 + ch]);
        bfr[f] = *reinterpret_cast<const s8v*>(&Bsm[cur][(wc * 64 + f * 16 + l15) * 64 + ch]);
      }
#pragma unroll
      for (int fr = 0; fr < 4; fr++)
#pragma unroll
        for (int fc = 0; fc < 4; fc++)
          acc[fr][fc] = __builtin_amdgcn_mfma_f32_16x16x32_bf16(af[fr], bfr[fc], acc[fr][fc], 0, 0, 0);
    }
    __builtin_amdgcn_s_setprio(0);
    __builtin_amdgcn_s_barrier();   // protect cur buffer before next stage overwrites
  }

  // fused epilogue: cols [nb,nb+128) all in one part (1024 % 128 == 0)
  const int pnum = nb >> 10;
#pragma unroll
  for (int fr = 0; fr < 4; fr++){
    int row  = mb + wr * 64 + fr * 16 + l4 * 4;   // +r, all 4 in same batch
    int b    = row >> 11;
    int nseq = row & 2047;
#pragma unroll
    for (int fc = 0; fc < 4; fc++){
      int col = nb + wc * 64 + fc * 16 + l15;
      int rem = col & 1023;
      int h = rem >> 6, d = rem & 63;
      int bh = b * 16 + h;
      if (pnum == 0){          // Q: scale, hi only
        size_t base = ((size_t)bh * SEQ + nseq) * 64 + d;
#pragma unroll
        for (int r = 0; r < 4; r++)
          Qh[base + (size_t)r * 64] = f2bf(acc[fr][fc][r] * QSCALE);
      } else if (pnum == 1){   // K: hi only
        size_t base = ((size_t)bh * SEQ + nseq) * 64 + d;
#pragma unroll
        for (int r = 0; r < 4; r++)
          Kh[base + (size_t)r * 64] = f2bf(acc[fr][fc][r]);
      } else {                 // V: transposed [bh][d][SEQ], 4 consecutive n
        size_t base = ((size_t)bh * 64 + d) * SEQ + nseq;
        *reinterpret_cast<ushort4*>(&Vth[base]) =
            make_ushort4(f2bf(acc[fr][fc][0]), f2bf(acc[fr][fc][1]),
                         f2bf(acc[fr][fc][2]), f2bf(acc[fr][fc][3]));
      }
    }
  }
}

// ---------------- out-projection GEMM (plain bf16, 1-term, dbuf + swizzle) ----------------
__global__ __launch_bounds__(256, 2) void k_gemm_out(
    const ushort_t* __restrict__ Ah, const ushort_t* __restrict__ Bth,
    float* __restrict__ C, const float* __restrict__ bias){
  __shared__ __align__(16) ushort_t Asm[2][GBM * GBK];
  __shared__ __align__(16) ushort_t Bsm[2][GBM * GBK];
  const int tid  = threadIdx.x;
  const int wave = tid >> 6, lane = tid & 63;
  const int mb = blockIdx.y * GBM, nb = blockIdx.x * GBN;
  const int wr = wave >> 1, wc = wave & 1;
  const int l15 = lane & 15, l4 = lane >> 4;
  const int rsub = lane >> 3;
  const int schunk = ((lane & 7) ^ rsub) * 8;
  f32x4 acc[4][4] = {};

  auto stage = [&](int buf, int kb){
    int k0 = kb * GBK;
#pragma unroll
    for (int i = 0; i < 4; i++){
      int row = (i * 4 + wave) * 8 + rsub;
      g2l16(Ah  + (size_t)(mb + row) * 1024 + k0 + schunk, &Asm[buf][(i * 4 + wave) * 512]);
      g2l16(Bth + (size_t)(nb + row) * 1024 + k0 + schunk, &Bsm[buf][(i * 4 + wave) * 512]);
    }
  };

  stage(0, 0);

  for (int kb = 0; kb < 16; kb++){
    const int cur = kb & 1;
    if (kb < 15){
      stage(cur ^ 1, kb + 1);
      asm volatile("s_waitcnt vmcnt(8)" ::: "memory");
    } else {
      asm volatile("s_waitcnt vmcnt(0)" ::: "memory");
    }
    __builtin_amdgcn_s_barrier();
    __builtin_amdgcn_s_setprio(1);
#pragma unroll
    for (int ks = 0; ks < 2; ks++){
      s8v af[4], bfr[4];
#pragma unroll
      for (int f = 0; f < 4; f++){
        int ch = (((ks * 4 + l4) ^ (l15 & 7)) << 3);
        af[f]  = *reinterpret_cast<const s8v*>(&Asm[cur][(wr * 64 + f * 16 + l15) * 64 + ch]);
        bfr[f] = *reinterpret_cast<const s8v*>(&Bsm[cur][(wc * 64 + f * 16 + l15) * 64 + ch]);
      }
#pragma unroll
      for (int fr = 0; fr < 4; fr++)
#pragma unroll
        for (int fc = 0; fc < 4; fc++)
          acc[fr][fc] = __builtin_amdgcn_mfma_f32_16x16x32_bf16(af[fr], bfr[fc], acc[fr][fc], 0, 0, 0);
    }
    __builtin_amdgcn_s_setprio(0);
    __builtin_amdgcn_s_barrier();
  }
#pragma unroll
  for (int fr = 0; fr < 4; fr++){
    int row = mb + wr * 64 + fr * 16 + l4 * 4;
#pragma unroll
    for (int fc = 0; fc < 4; fc++){
      int col = nb + wc * 64 + fc * 16 + l15;
      float bv = bias[col];
#pragma unroll
      for (int r = 0; r < 4; r++)
        C[(size_t)(row + r) * 1024 + col] = acc[fr][fc][r] + bv;
    }
  }
}

// ---------------- flash attention ----------------
// QBLK=64: grid 1024 = exactly 4 blocks/CU (LDS 33.8KB). 4 waves x 16 q-rows.
// QK^T: 1-term (Qh*Kh) in log2 units. Softmax: fixed bias MFIX. PV: 1-term.
// K double-buffered; V single-buffered (its load hides under QK+softmax).
// Wait ledger per wave-iter (2 K loads + 2 V loads): pre-QK vmcnt(4), pre-PV vmcnt(2).
__global__ __launch_bounds__(256, 4) void k_flash(
    const ushort_t* __restrict__ Qh, const ushort_t* __restrict__ Kh,
    const ushort_t* __restrict__ Vth, ushort_t* __restrict__ Ah){
  __shared__ __align__(16) ushort_t KhS[2][64 * 64];
  __shared__ __align__(16) ushort_t VhS[64 * 64];
  __shared__ __align__(16) ushort_t PhS[64 * 72];
  const int lid = blockIdx.x;             // 0..1023
  const int xcd = lid & 7, g = lid >> 3;  // 8 XCDs x 128 blocks
  const int bh = xcd * 4 + (g & 3);       // each XCD owns 4 heads (K/V L2-resident)
  const int qb = (g >> 2) * 64;
  const int tid = threadIdx.x, wave = tid >> 6, lane = tid & 63;
  const int l15 = lane & 15, l4 = lane >> 4;
  const int b = bh >> 4, h = bh & 15;
  const size_t hbase = (size_t)bh * SEQ * 64;
  const int rsub = lane >> 3;
  const int schunk = ((lane & 7) ^ rsub) * 8;

  // Q fragments (hi only), 16 q-rows per wave
  s8v qhf[2];
#pragma unroll
  for (int ks = 0; ks < 2; ks++){
    size_t off = hbase + (size_t)(qb + wave * 16 + l15) * 64 + ks * 32 + l4 * 8;
    qhf[ks] = *reinterpret_cast<const s8v*>(&Qh[off]);
  }

  f32x4 o[4] = {};
  float lsum[4] = {};

  auto stageK = [&](int buf, int kt){
    int kvb = kt * 64;
#pragma unroll
    for (int i = 0; i < 2; i++){
      int row = (i * 4 + wave) * 8 + rsub;
      g2l16(Kh + hbase + (size_t)(kvb + row) * 64 + schunk, &KhS[buf][(i * 4 + wave) * 512]);
    }
  };
  auto stageV = [&](int kt){
    int kvb = kt * 64;
#pragma unroll
    for (int i = 0; i < 2; i++){
      int row = (i * 4 + wave) * 8 + rsub;
      g2l16(Vth + ((size_t)bh * 64 + row) * SEQ + kvb + schunk, &VhS[(i * 4 + wave) * 512]);
    }
  };

  stageK(0, 0);

  for (int kt = 0; kt < 32; kt++){
    const int cur = kt & 1;
    stageV(kt);                     // V[kt] lands during QK+softmax
    if (kt < 31){
      stageK(cur ^ 1, kt + 1);      // K[kt+1] stays in flight across the whole iter
      asm volatile("s_waitcnt vmcnt(4)" ::: "memory");  // K[kt] landed
    } else {
      asm volatile("s_waitcnt vmcnt(2)" ::: "memory");
    }
    __builtin_amdgcn_s_barrier();

    // S = Qh Kh^T (1-term), swizzled LDS reads
    f32x4 s[4] = {};
    __builtin_amdgcn_s_setprio(1);
#pragma unroll
    for (int ks = 0; ks < 2; ks++)
#pragma unroll
      for (int fc = 0; fc < 4; fc++){
        int rK = fc * 16 + l15;
        int ch = ((ks * 4 + l4) ^ (rK & 7)) << 3;
        s8v kh = *reinterpret_cast<const s8v*>(&KhS[cur][rK * 64 + ch]);
        s[fc] = __builtin_amdgcn_mfma_f32_16x16x32_bf16(qhf[ks], kh, s[fc], 0, 0, 0);
      }
    __builtin_amdgcn_s_setprio(0);

    // fixed-max softmax: p = exp2(s - MFIX); truncation bf16 store
#pragma unroll
    for (int fc = 0; fc < 4; fc++)
#pragma unroll
      for (int r = 0; r < 4; r++){
        float p = __builtin_amdgcn_exp2f(s[fc][r] - MFIX);
        lsum[r] += p;
        int prow = wave * 16 + l4 * 4 + r;
        int col  = (fc * 16 + l15) ^ (((prow >> 2) & 3) << 3);
        PhS[prow * 72 + col] = f2bf_trunc(p);
      }

    if (kt < 31){
      asm volatile("s_waitcnt vmcnt(2)" ::: "memory");  // V[kt] landed (K[kt+1] in flight)
    } else {
      asm volatile("s_waitcnt vmcnt(0)" ::: "memory");
    }
    __builtin_amdgcn_s_barrier();

    // O += P V
    __builtin_amdgcn_s_setprio(1);
#pragma unroll
    for (int c = 0; c < 2; c++){
      int prow = wave * 16 + l15;
      int u = (prow >> 2) & 3;
      s8v pa = *reinterpret_cast<const s8v*>(&PhS[prow * 72 + (((c * 4 + l4) ^ u) << 3)]);
#pragma unroll
      for (int fd = 0; fd < 4; fd++){
        int rV = fd * 16 + l15;
        int ch = ((c * 4 + l4) ^ (rV & 7)) << 3;
        s8v vh = *reinterpret_cast<const s8v*>(&VhS[rV * 64 + ch]);
        o[fd] = __builtin_amdgcn_mfma_f32_16x16x32_bf16(pa, vh, o[fd], 0, 0, 0);
      }
    }
    __builtin_amdgcn_s_setprio(0);
    __builtin_amdgcn_s_barrier();   // V buffer + K[cur] free for next iter's stages
  }

  // epilogue: reduce lsum across the 16-lane row group (once), write bf16 Ah
#pragma unroll
  for (int msk = 1; msk < 16; msk <<= 1)
#pragma unroll
    for (int r = 0; r < 4; r++)
      lsum[r] += __shfl_xor(lsum[r], msk);
#pragma unroll
  for (int r = 0; r < 4; r++){
    float inv = 1.f / lsum[r];
    int n = qb + wave * 16 + l4 * 4 + r;
    size_t rowbase = (size_t)(b * SEQ + n) * 1024 + h * 64;
#pragma unroll
    for (int fd = 0; fd < 4; fd++)
      Ah[rowbase + fd * 16 + l15] = f2bf(o[fd][r] * inv);
  }
}

// ---------------- host launch ----------------
extern "C" void kernel_launch(void* const* d_in, const int* in_sizes, int n_in,
                              void* d_out, int out_size, void* d_ws, size_t ws_size,
                              hipStream_t stream){
  const float* x     = (const float*)d_in[0];
  const float* w_qkv = (const float*)d_in[1];
  const float* w_out = (const float*)d_in[2];
  const float* b_out = (const float*)d_in[3];
  float* out = (float*)d_out;
  char* ws = (char*)d_ws;

  ushort_t* Xh    = (ushort_t*)(ws);                      //  8 MB
  ushort_t* Wqt_h = (ushort_t*)(ws + 8388608);            //  6 MB
  ushort_t* Wot_h = (ushort_t*)(ws + 14680064);           //  2 MB
  ushort_t* Qh    = (ushort_t*)(ws + 16777216);           //  8 MB
  ushort_t* Kh    = (ushort_t*)(ws + 25165824);           //  8 MB
  ushort_t* Vth   = (ushort_t*)(ws + 33554432);           //  8 MB
  ushort_t* Ah    = (ushort_t*)(ws + 41943040);           //  8 MB

  // 1. x -> Xh (bf16)
  k_cvt<<<4096, 256, 0, stream>>>(x, Xh, ROWS * PDIM / 4);
  // 2. w_qkv [1024][3072] -> Wqt_h [3072][1024] (bf16 hi)
  k_tcvt<<<dim3(48, 16), 256, 0, stream>>>(w_qkv, 1024, 3072, Wqt_h);
  // 3. w_out [1024][1024] -> Wot_h [1024][1024] (bf16 hi)
  k_tcvt<<<dim3(16, 16), 256, 0, stream>>>(w_out, 1024, 1024, Wot_h);
  // 4. QKV projection (1-term) with fused per-head epilogue
  k_gemm_qkv<<<dim3(24, 32), 256, 0, stream>>>(Xh, Wqt_h, Qh, Kh, Vth);
  // 5. attention -> Ah (bf16)
  k_flash<<<1024, 256, 0, stream>>>(Qh, Kh, Vth, Ah);
  // 6. out = Ah @ Wot + b_out
  k_gemm_out<<<dim3(8, 32), 256, 0, stream>>>(Ah, Wot_h, out, b_out);
}

// Round 8
// 127.904 us; speedup vs baseline: 1.3205x; 1.0448x over previous
//
#include <hip/hip_runtime.h>
#include <hip/hip_bf16.h>
#include <stdint.h>

// ---------------- problem constants ----------------
#define PDIM   1024
#define HEADS  16
#define DHEAD  64
#define BATCH  2
#define SEQ    2048
#define ROWS   (BATCH*SEQ)     // 4096
#define NBH    (BATCH*HEADS)   // 32

typedef __attribute__((ext_vector_type(8))) short s8v;    // 8 x bf16 (4 VGPR)
typedef __attribute__((ext_vector_type(4))) float f32x4;  // MFMA accumulator
typedef unsigned short ushort_t;
typedef unsigned int   uint32;

// Q pre-scale: DIM_HEAD^-0.5 * log2(e)  (softmax done in exp2 units)
#define QSCALE 0.18033688011112042f
// fixed softmax bias (log2 units): p = exp2(s - MFIX); cancels in num/denom
#define MFIX 12.0f

// ---------------- helpers ----------------
__device__ __forceinline__ ushort_t f2bf(float x){
  union { float f; uint32 u; } v; v.f = x;
  uint32 r = v.u + 0x7FFFu + ((v.u >> 16) & 1u);   // RTN-even
  return (ushort_t)(r >> 16);
}
__device__ __forceinline__ uint32 cvt_pk_bf16(float lo, float hi){
  uint32 r;
  asm("v_cvt_pk_bf16_f32 %0, %1, %2" : "=v"(r) : "v"(lo), "v"(hi));
  return r;   // bf16(lo) in [15:0], bf16(hi) in [31:16]
}

typedef const __attribute__((address_space(1))) void* gas_ptr;
typedef __attribute__((address_space(3))) void*       las_ptr;
__device__ __forceinline__ void g2l16(const void* g, void* l){
  // dest = wave-uniform LDS base; HW adds lane*16
  __builtin_amdgcn_global_load_lds((gas_ptr)g, (las_ptr)l, 16, 0, 0);
}

// ---------------- fp32 -> bf16 convert (hi only) ----------------
__global__ __launch_bounds__(256) void k_cvt(const float* __restrict__ src,
                                             ushort_t* __restrict__ dst, int n4){
  int i = blockIdx.x * 256 + threadIdx.x;
  if (i >= n4) return;
  float4 v = reinterpret_cast<const float4*>(src)[i];
  reinterpret_cast<ushort4*>(dst)[i] =
      make_ushort4(f2bf(v.x), f2bf(v.y), f2bf(v.z), f2bf(v.w));
}

// ---------------- transpose: src[R][C] f32 -> dst[C][R] bf16 (hi only) ----------------
__global__ __launch_bounds__(256) void k_tcvt(const float* __restrict__ src, int R, int C,
                                              ushort_t* __restrict__ dh){
  __shared__ float tile[64][65];
  int cb = blockIdx.x * 64, rb = blockIdx.y * 64;
  int t = threadIdx.x;
  int lw = t >> 6;      // wave id 0..3
  int lc = t & 63;      // lane 0..63
#pragma unroll
  for (int i = 0; i < 16; i++){
    int r = i * 4 + lw;
    tile[r][lc] = src[(size_t)(rb + r) * C + cb + lc];
  }
  __syncthreads();
#pragma unroll
  for (int i = 0; i < 16; i++){
    int c = i * 4 + lw;
    dh[(size_t)(cb + c) * R + rb + lc] = f2bf(tile[lc][c]);
  }
}

// ---------------- GEMM core (128x128 tile, BK=64, 4 waves, dbuf + swizzle) ----------------
#define GBM 128
#define GBN 128
#define GBK 64

// ---------------- QKV projection GEMM, fused per-head epilogue ----------------
// A = Xh [4096][1024] bf16, B = Wqt_h [3072][1024] bf16 (1-term).
// Epilogue writes directly: Qh [bh][n][64] (scaled), Kh [bh][n][64], Vth [bh][d][SEQ].
__global__ __launch_bounds__(256, 2) void k_gemm_qkv(
    const ushort_t* __restrict__ Xh, const ushort_t* __restrict__ Wqt_h,
    ushort_t* __restrict__ Qh, ushort_t* __restrict__ Kh, ushort_t* __restrict__ Vth){
  __shared__ __align__(16) ushort_t Asm[2][GBM * GBK];
  __shared__ __align__(16) ushort_t Bsm[2][GBM * GBK];
  const int tid  = threadIdx.x;
  const int wave = tid >> 6, lane = tid & 63;
  const int mb = blockIdx.y * GBM, nb = blockIdx.x * GBN;
  const int wr = wave >> 1, wc = wave & 1;
  const int l15 = lane & 15, l4 = lane >> 4;
  const int rsub = lane >> 3;
  const int schunk = ((lane & 7) ^ rsub) * 8;  // source-swizzled chunk
  f32x4 acc[4][4] = {};

  auto stage = [&](int buf, int kb){
    int k0 = kb * GBK;
#pragma unroll
    for (int i = 0; i < 4; i++){
      int row = (i * 4 + wave) * 8 + rsub;
      g2l16(Xh    + (size_t)(mb + row) * 1024 + k0 + schunk, &Asm[buf][(i * 4 + wave) * 512]);
      g2l16(Wqt_h + (size_t)(nb + row) * 1024 + k0 + schunk, &Bsm[buf][(i * 4 + wave) * 512]);
    }
  };

  stage(0, 0);

  for (int kb = 0; kb < 16; kb++){
    const int cur = kb & 1;
    if (kb < 15){
      stage(cur ^ 1, kb + 1);                          // next tile's 8 loads in flight
      asm volatile("s_waitcnt vmcnt(8)" ::: "memory"); // current tile's 8 have landed
    } else {
      asm volatile("s_waitcnt vmcnt(0)" ::: "memory");
    }
    __builtin_amdgcn_s_barrier();
    __builtin_amdgcn_s_setprio(1);
#pragma unroll
    for (int ks = 0; ks < 2; ks++){
      s8v af[4], bfr[4];
#pragma unroll
      for (int f = 0; f < 4; f++){
        int ch = (((ks * 4 + l4) ^ (l15 & 7)) << 3);
        af[f]  = *reinterpret_cast<const s8v*>(&Asm[cur][(wr * 64 + f * 16 + l15) * 64 + ch]);
        bfr[f] = *reinterpret_cast<const s8v*>(&Bsm[cur][(wc * 64 + f * 16 + l15) * 64 + ch]);
      }
#pragma unroll
      for (int fr = 0; fr < 4; fr++)
#pragma unroll
        for (int fc = 0; fc < 4; fc++)
          acc[fr][fc] = __builtin_amdgcn_mfma_f32_16x16x32_bf16(af[fr], bfr[fc], acc[fr][fc], 0, 0, 0);
    }
    __builtin_amdgcn_s_setprio(0);
    __builtin_amdgcn_s_barrier();   // protect cur buffer before next stage overwrites
  }

  // fused epilogue: cols [nb,nb+128) all in one part (1024 % 128 == 0)
  const int pnum = nb >> 10;
#pragma unroll
  for (int fr = 0; fr < 4; fr++){
    int row  = mb + wr * 64 + fr * 16 + l4 * 4;   // +r, all 4 in same batch
    int b    = row >> 11;
    int nseq = row & 2047;
#pragma unroll
    for (int fc = 0; fc < 4; fc++){
      int col = nb + wc * 64 + fc * 16 + l15;
      int rem = col & 1023;
      int h = rem >> 6, d = rem & 63;
      int bh = b * 16 + h;
      if (pnum == 0){          // Q: scale, hi only
        size_t base = ((size_t)bh * SEQ + nseq) * 64 + d;
#pragma unroll
        for (int r = 0; r < 4; r++)
          Qh[base + (size_t)r * 64] = f2bf(acc[fr][fc][r] * QSCALE);
      } else if (pnum == 1){   // K: hi only
        size_t base = ((size_t)bh * SEQ + nseq) * 64 + d;
#pragma unroll
        for (int r = 0; r < 4; r++)
          Kh[base + (size_t)r * 64] = f2bf(acc[fr][fc][r]);
      } else {                 // V: transposed [bh][d][SEQ], 4 consecutive n
        size_t base = ((size_t)bh * 64 + d) * SEQ + nseq;
        *reinterpret_cast<ushort4*>(&Vth[base]) =
            make_ushort4(f2bf(acc[fr][fc][0]), f2bf(acc[fr][fc][1]),
                         f2bf(acc[fr][fc][2]), f2bf(acc[fr][fc][3]));
      }
    }
  }
}

// ---------------- out-projection GEMM (plain bf16, 1-term, dbuf + swizzle) ----------------
__global__ __launch_bounds__(256, 2) void k_gemm_out(
    const ushort_t* __restrict__ Ah, const ushort_t* __restrict__ Bth,
    float* __restrict__ C, const float* __restrict__ bias){
  __shared__ __align__(16) ushort_t Asm[2][GBM * GBK];
  __shared__ __align__(16) ushort_t Bsm[2][GBM * GBK];
  const int tid  = threadIdx.x;
  const int wave = tid >> 6, lane = tid & 63;
  const int mb = blockIdx.y * GBM, nb = blockIdx.x * GBN;
  const int wr = wave >> 1, wc = wave & 1;
  const int l15 = lane & 15, l4 = lane >> 4;
  const int rsub = lane >> 3;
  const int schunk = ((lane & 7) ^ rsub) * 8;
  f32x4 acc[4][4] = {};

  auto stage = [&](int buf, int kb){
    int k0 = kb * GBK;
#pragma unroll
    for (int i = 0; i < 4; i++){
      int row = (i * 4 + wave) * 8 + rsub;
      g2l16(Ah  + (size_t)(mb + row) * 1024 + k0 + schunk, &Asm[buf][(i * 4 + wave) * 512]);
      g2l16(Bth + (size_t)(nb + row) * 1024 + k0 + schunk, &Bsm[buf][(i * 4 + wave) * 512]);
    }
  };

  stage(0, 0);

  for (int kb = 0; kb < 16; kb++){
    const int cur = kb & 1;
    if (kb < 15){
      stage(cur ^ 1, kb + 1);
      asm volatile("s_waitcnt vmcnt(8)" ::: "memory");
    } else {
      asm volatile("s_waitcnt vmcnt(0)" ::: "memory");
    }
    __builtin_amdgcn_s_barrier();
    __builtin_amdgcn_s_setprio(1);
#pragma unroll
    for (int ks = 0; ks < 2; ks++){
      s8v af[4], bfr[4];
#pragma unroll
      for (int f = 0; f < 4; f++){
        int ch = (((ks * 4 + l4) ^ (l15 & 7)) << 3);
        af[f]  = *reinterpret_cast<const s8v*>(&Asm[cur][(wr * 64 + f * 16 + l15) * 64 + ch]);
        bfr[f] = *reinterpret_cast<const s8v*>(&Bsm[cur][(wc * 64 + f * 16 + l15) * 64 + ch]);
      }
#pragma unroll
      for (int fr = 0; fr < 4; fr++)
#pragma unroll
        for (int fc = 0; fc < 4; fc++)
          acc[fr][fc] = __builtin_amdgcn_mfma_f32_16x16x32_bf16(af[fr], bfr[fc], acc[fr][fc], 0, 0, 0);
    }
    __builtin_amdgcn_s_setprio(0);
    __builtin_amdgcn_s_barrier();
  }
#pragma unroll
  for (int fr = 0; fr < 4; fr++){
    int row = mb + wr * 64 + fr * 16 + l4 * 4;
#pragma unroll
    for (int fc = 0; fc < 4; fc++){
      int col = nb + wc * 64 + fc * 16 + l15;
      float bv = bias[col];
#pragma unroll
      for (int r = 0; r < 4; r++)
        C[(size_t)(row + r) * 1024 + col] = acc[fr][fc][r] + bv;
    }
  }
}

// ---------------- flash attention (swapped-QK^T, packed P path) ----------------
// QBLK=64: grid 1024 = exactly 4 blocks/CU (LDS 33.8KB). 4 waves x 16 q-rows.
// QK^T computed SWAPPED: s = mfma(K, Q) -> S^T; lane (l15,l4) holds
// S[kv = fc*16 + l4*4 + r][q = l15] — all 16 P values belong to q=l15.
//  -> lsum is a per-lane SCALAR (reduced once in epilogue)
//  -> P store = 8 cvt_pk + 4 ds_write_b64 (vs 16 scalar writes)
// P LDS: [64 q][72] ushorts, granule-16 XOR by (q&3) on both write and read.
// K double-buffered; V single-buffered. Ledger: pre-QK vmcnt(4), pre-PV vmcnt(2).
__global__ __launch_bounds__(256, 4) void k_flash(
    const ushort_t* __restrict__ Qh, const ushort_t* __restrict__ Kh,
    const ushort_t* __restrict__ Vth, ushort_t* __restrict__ Ah){
  __shared__ __align__(16) ushort_t KhS[2][64 * 64];
  __shared__ __align__(16) ushort_t VhS[64 * 64];
  __shared__ __align__(16) ushort_t PhS[64 * 72];
  const int lid = blockIdx.x;             // 0..1023
  const int xcd = lid & 7, g = lid >> 3;  // 8 XCDs x 128 blocks
  const int bh = xcd * 4 + (g & 3);       // each XCD owns 4 heads (K/V L2-resident)
  const int qb = (g >> 2) * 64;
  const int tid = threadIdx.x, wave = tid >> 6, lane = tid & 63;
  const int l15 = lane & 15, l4 = lane >> 4;
  const int b = bh >> 4, h = bh & 15;
  const size_t hbase = (size_t)bh * SEQ * 64;
  const int rsub = lane >> 3;
  const int schunk = ((lane & 7) ^ rsub) * 8;
  const int prow  = wave * 16 + l15;      // this lane's q-row (write AND read)
  const int pkey  = l15 & 3;              // granule-16 XOR key

  // Q fragments (hi only), 16 q-rows per wave; also the B-operand for swapped QK
  s8v qhf[2];
#pragma unroll
  for (int ks = 0; ks < 2; ks++){
    size_t off = hbase + (size_t)(qb + wave * 16 + l15) * 64 + ks * 32 + l4 * 8;
    qhf[ks] = *reinterpret_cast<const s8v*>(&Qh[off]);
  }

  f32x4 o[4] = {};
  float lsum = 0.f;

  auto stageK = [&](int buf, int kt){
    int kvb = kt * 64;
#pragma unroll
    for (int i = 0; i < 2; i++){
      int row = (i * 4 + wave) * 8 + rsub;
      g2l16(Kh + hbase + (size_t)(kvb + row) * 64 + schunk, &KhS[buf][(i * 4 + wave) * 512]);
    }
  };
  auto stageV = [&](int kt){
    int kvb = kt * 64;
#pragma unroll
    for (int i = 0; i < 2; i++){
      int row = (i * 4 + wave) * 8 + rsub;
      g2l16(Vth + ((size_t)bh * 64 + row) * SEQ + kvb + schunk, &VhS[(i * 4 + wave) * 512]);
    }
  };

  stageK(0, 0);

  for (int kt = 0; kt < 32; kt++){
    const int cur = kt & 1;
    stageV(kt);                     // V[kt] lands during QK+softmax
    if (kt < 31){
      stageK(cur ^ 1, kt + 1);      // K[kt+1] stays in flight across the whole iter
      asm volatile("s_waitcnt vmcnt(4)" ::: "memory");  // K[kt] landed
    } else {
      asm volatile("s_waitcnt vmcnt(2)" ::: "memory");
    }
    __builtin_amdgcn_s_barrier();

    // S^T = Kh Qh^T (swapped operands; fragment reads identical to before)
    f32x4 s[4] = {};
    __builtin_amdgcn_s_setprio(1);
#pragma unroll
    for (int ks = 0; ks < 2; ks++)
#pragma unroll
      for (int fc = 0; fc < 4; fc++){
        int rK = fc * 16 + l15;
        int ch = ((ks * 4 + l4) ^ (rK & 7)) << 3;
        s8v kh = *reinterpret_cast<const s8v*>(&KhS[cur][rK * 64 + ch]);
        s[fc] = __builtin_amdgcn_mfma_f32_16x16x32_bf16(kh, qhf[ks], s[fc], 0, 0, 0);
      }
    __builtin_amdgcn_s_setprio(0);

    // fixed-max softmax on S^T: all 16 values are q=prow, kv = fc*16 + l4*4 + r
#pragma unroll
    for (int fc = 0; fc < 4; fc++){
      float p0 = __builtin_amdgcn_exp2f(s[fc][0] - MFIX);
      float p1 = __builtin_amdgcn_exp2f(s[fc][1] - MFIX);
      float p2 = __builtin_amdgcn_exp2f(s[fc][2] - MFIX);
      float p3 = __builtin_amdgcn_exp2f(s[fc][3] - MFIX);
      lsum += (p0 + p1) + (p2 + p3);
      uint2 w;
      w.x = cvt_pk_bf16(p0, p1);
      w.y = cvt_pk_bf16(p2, p3);
      // kv offset 16*fc + 4*l4, granule-16 XOR by pkey
      *reinterpret_cast<uint2*>(&PhS[prow * 72 + ((fc ^ pkey) << 4) + (l4 << 2)]) = w;
    }

    if (kt < 31){
      asm volatile("s_waitcnt vmcnt(2)" ::: "memory");  // V[kt] landed (K[kt+1] in flight)
    } else {
      asm volatile("s_waitcnt vmcnt(0)" ::: "memory");
    }
    __builtin_amdgcn_s_barrier();

    // O += P V ; pa = A-fragment: P[q=prow][kv = c*32 + l4*8 .. +8)
    __builtin_amdgcn_s_setprio(1);
#pragma unroll
    for (int c = 0; c < 2; c++){
      int gidx = (2 * c + (l4 >> 1)) ^ pkey;
      s8v pa = *reinterpret_cast<const s8v*>(&PhS[prow * 72 + (gidx << 4) + ((l4 & 1) << 3)]);
#pragma unroll
      for (int fd = 0; fd < 4; fd++){
        int rV = fd * 16 + l15;
        int ch = ((c * 4 + l4) ^ (rV & 7)) << 3;
        s8v vh = *reinterpret_cast<const s8v*>(&VhS[rV * 64 + ch]);
        o[fd] = __builtin_amdgcn_mfma_f32_16x16x32_bf16(pa, vh, o[fd], 0, 0, 0);
      }
    }
    __builtin_amdgcn_s_setprio(0);
    __builtin_amdgcn_s_barrier();   // V buffer + K[cur] free for next iter's stages
  }

  // epilogue: lsum lives per-lane for q=prow; reduce over the 4 l4-groups,
  // then fetch lsum for output rows q' = l4*4 + r via lane shuffle.
  lsum += __shfl_xor(lsum, 16);
  lsum += __shfl_xor(lsum, 32);
#pragma unroll
  for (int r = 0; r < 4; r++){
    float inv = 1.f / __shfl(lsum, l4 * 4 + r);   // source lane l4*4+r holds q'=l4*4+r
    int n = qb + wave * 16 + l4 * 4 + r;
    size_t rowbase = (size_t)(b * SEQ + n) * 1024 + h * 64;
#pragma unroll
    for (int fd = 0; fd < 4; fd++)
      Ah[rowbase + fd * 16 + l15] = f2bf(o[fd][r] * inv);
  }
}

// ---------------- host launch ----------------
extern "C" void kernel_launch(void* const* d_in, const int* in_sizes, int n_in,
                              void* d_out, int out_size, void* d_ws, size_t ws_size,
                              hipStream_t stream){
  const float* x     = (const float*)d_in[0];
  const float* w_qkv = (const float*)d_in[1];
  const float* w_out = (const float*)d_in[2];
  const float* b_out = (const float*)d_in[3];
  float* out = (float*)d_out;
  char* ws = (char*)d_ws;

  ushort_t* Xh    = (ushort_t*)(ws);                      //  8 MB
  ushort_t* Wqt_h = (ushort_t*)(ws + 8388608);            //  6 MB
  ushort_t* Wot_h = (ushort_t*)(ws + 14680064);           //  2 MB
  ushort_t* Qh    = (ushort_t*)(ws + 16777216);           //  8 MB
  ushort_t* Kh    = (ushort_t*)(ws + 25165824);           //  8 MB
  ushort_t* Vth   = (ushort_t*)(ws + 33554432);           //  8 MB
  ushort_t* Ah    = (ushort_t*)(ws + 41943040);           //  8 MB

  // 1. x -> Xh (bf16)
  k_cvt<<<4096, 256, 0, stream>>>(x, Xh, ROWS * PDIM / 4);
  // 2. w_qkv [1024][3072] -> Wqt_h [3072][1024] (bf16 hi)
  k_tcvt<<<dim3(48, 16), 256, 0, stream>>>(w_qkv, 1024, 3072, Wqt_h);
  // 3. w_out [1024][1024] -> Wot_h [1024][1024] (bf16 hi)
  k_tcvt<<<dim3(16, 16), 256, 0, stream>>>(w_out, 1024, 1024, Wot_h);
  // 4. QKV projection (1-term) with fused per-head epilogue
  k_gemm_qkv<<<dim3(24, 32), 256, 0, stream>>>(Xh, Wqt_h, Qh, Kh, Vth);
  // 5. attention -> Ah (bf16)
  k_flash<<<1024, 256, 0, stream>>>(Qh, Kh, Vth, Ah);
  // 6. out = Ah @ Wot + b_out
  k_gemm_out<<<dim3(8, 32), 256, 0, stream>>>(Ah, Wot_h, out, b_out);
}

// Round 9
// 115.664 us; speedup vs baseline: 1.4603x; 1.1058x over previous
//
#include <hip/hip_runtime.h>
#include <hip/hip_bf16.h>
#include <stdint.h>

// ---------------- problem constants ----------------
#define PDIM   1024
#define HEADS  16
#define DHEAD  64
#define BATCH  2
#define SEQ    2048
#define ROWS   (BATCH*SEQ)     // 4096
#define NBH    (BATCH*HEADS)   // 32

typedef __attribute__((ext_vector_type(8))) short s8v;    // 8 x bf16 (4 VGPR)
typedef __attribute__((ext_vector_type(4))) float f32x4;  // MFMA accumulator
typedef unsigned short ushort_t;
typedef unsigned int   uint32;

// Q pre-scale: DIM_HEAD^-0.5 * log2(e)  (softmax done in exp2 units)
#define QSCALE 0.18033688011112042f
// fixed softmax bias (log2 units): p = exp2(s - MFIX); cancels in num/denom
#define MFIX 12.0f

// ---------------- helpers ----------------
__device__ __forceinline__ ushort_t f2bf(float x){
  union { float f; uint32 u; } v; v.f = x;
  uint32 r = v.u + 0x7FFFu + ((v.u >> 16) & 1u);   // RTN-even
  return (ushort_t)(r >> 16);
}
__device__ __forceinline__ uint32 cvt_pk_bf16(float lo, float hi){
  uint32 r;
  asm("v_cvt_pk_bf16_f32 %0, %1, %2" : "=v"(r) : "v"(lo), "v"(hi));
  return r;   // bf16(lo) in [15:0], bf16(hi) in [31:16]
}

typedef const __attribute__((address_space(1))) void* gas_ptr;
typedef __attribute__((address_space(3))) void*       las_ptr;
__device__ __forceinline__ void g2l16(const void* g, void* l){
  // dest = wave-uniform LDS base; HW adds lane*16
  __builtin_amdgcn_global_load_lds((gas_ptr)g, (las_ptr)l, 16, 0, 0);
}

// ---------------- fused prep: x cvt + w_qkv tcvt + w_out tcvt ----------------
// blocks [0,4096): x -> Xh (float4 each thread)
// blocks [4096,4864): w_qkv [1024][3072] -> Wqt_h [3072][1024]
// blocks [4864,5120): w_out [1024][1024] -> Wot_h [1024][1024]
__global__ __launch_bounds__(256) void k_prep(
    const float* __restrict__ x, const float* __restrict__ w_qkv,
    const float* __restrict__ w_out,
    ushort_t* __restrict__ Xh, ushort_t* __restrict__ Wqt_h,
    ushort_t* __restrict__ Wot_h){
  __shared__ float tile[64][65];
  const int bid = blockIdx.x;
  if (bid < 4096){
    int i = bid * 256 + threadIdx.x;
    float4 v = reinterpret_cast<const float4*>(x)[i];
    reinterpret_cast<ushort4*>(Xh)[i] =
        make_ushort4(f2bf(v.x), f2bf(v.y), f2bf(v.z), f2bf(v.w));
    return;
  }
  const float* src; ushort_t* dst; int R, C, cb, rb;
  if (bid < 4864){
    int t = bid - 4096; src = w_qkv; dst = Wqt_h; R = 1024; C = 3072;
    cb = (t % 48) * 64; rb = (t / 48) * 64;
  } else {
    int t = bid - 4864; src = w_out; dst = Wot_h; R = 1024; C = 1024;
    cb = (t % 16) * 64; rb = (t / 16) * 64;
  }
  int t = threadIdx.x;
  int lw = t >> 6, lc = t & 63;
#pragma unroll
  for (int i = 0; i < 16; i++){
    int r = i * 4 + lw;
    tile[r][lc] = src[(size_t)(rb + r) * C + cb + lc];
  }
  __syncthreads();
#pragma unroll
  for (int i = 0; i < 16; i++){
    int c = i * 4 + lw;
    dst[(size_t)(cb + c) * R + rb + lc] = f2bf(tile[lc][c]);
  }
}

// ---------------- GEMM core (128x128 tile, BK=64, 4 waves, dbuf + swizzle) ----------------
#define GBM 128
#define GBN 128
#define GBK 64

// ---------------- QKV projection GEMM, fused per-head epilogue ----------------
__global__ __launch_bounds__(256, 2) void k_gemm_qkv(
    const ushort_t* __restrict__ Xh, const ushort_t* __restrict__ Wqt_h,
    ushort_t* __restrict__ Qh, ushort_t* __restrict__ Kh, ushort_t* __restrict__ Vth){
  __shared__ __align__(16) ushort_t Asm[2][GBM * GBK];
  __shared__ __align__(16) ushort_t Bsm[2][GBM * GBK];
  const int tid  = threadIdx.x;
  const int wave = tid >> 6, lane = tid & 63;
  const int mb = blockIdx.y * GBM, nb = blockIdx.x * GBN;
  const int wr = wave >> 1, wc = wave & 1;
  const int l15 = lane & 15, l4 = lane >> 4;
  const int rsub = lane >> 3;
  const int schunk = ((lane & 7) ^ rsub) * 8;  // source-swizzled chunk
  f32x4 acc[4][4] = {};

  auto stage = [&](int buf, int kb){
    int k0 = kb * GBK;
#pragma unroll
    for (int i = 0; i < 4; i++){
      int row = (i * 4 + wave) * 8 + rsub;
      g2l16(Xh    + (size_t)(mb + row) * 1024 + k0 + schunk, &Asm[buf][(i * 4 + wave) * 512]);
      g2l16(Wqt_h + (size_t)(nb + row) * 1024 + k0 + schunk, &Bsm[buf][(i * 4 + wave) * 512]);
    }
  };

  stage(0, 0);

  for (int kb = 0; kb < 16; kb++){
    const int cur = kb & 1;
    if (kb < 15){
      stage(cur ^ 1, kb + 1);
      asm volatile("s_waitcnt vmcnt(8)" ::: "memory");
    } else {
      asm volatile("s_waitcnt vmcnt(0)" ::: "memory");
    }
    __builtin_amdgcn_s_barrier();
    __builtin_amdgcn_s_setprio(1);
#pragma unroll
    for (int ks = 0; ks < 2; ks++){
      s8v af[4], bfr[4];
#pragma unroll
      for (int f = 0; f < 4; f++){
        int ch = (((ks * 4 + l4) ^ (l15 & 7)) << 3);
        af[f]  = *reinterpret_cast<const s8v*>(&Asm[cur][(wr * 64 + f * 16 + l15) * 64 + ch]);
        bfr[f] = *reinterpret_cast<const s8v*>(&Bsm[cur][(wc * 64 + f * 16 + l15) * 64 + ch]);
      }
#pragma unroll
      for (int fr = 0; fr < 4; fr++)
#pragma unroll
        for (int fc = 0; fc < 4; fc++)
          acc[fr][fc] = __builtin_amdgcn_mfma_f32_16x16x32_bf16(af[fr], bfr[fc], acc[fr][fc], 0, 0, 0);
    }
    __builtin_amdgcn_s_setprio(0);
    __builtin_amdgcn_s_barrier();
  }

  // fused epilogue: cols [nb,nb+128) all in one part (1024 % 128 == 0)
  const int pnum = nb >> 10;
#pragma unroll
  for (int fr = 0; fr < 4; fr++){
    int row  = mb + wr * 64 + fr * 16 + l4 * 4;
    int b    = row >> 11;
    int nseq = row & 2047;
#pragma unroll
    for (int fc = 0; fc < 4; fc++){
      int col = nb + wc * 64 + fc * 16 + l15;
      int rem = col & 1023;
      int h = rem >> 6, d = rem & 63;
      int bh = b * 16 + h;
      if (pnum == 0){          // Q: scale, hi only
        size_t base = ((size_t)bh * SEQ + nseq) * 64 + d;
#pragma unroll
        for (int r = 0; r < 4; r++)
          Qh[base + (size_t)r * 64] = f2bf(acc[fr][fc][r] * QSCALE);
      } else if (pnum == 1){   // K: hi only
        size_t base = ((size_t)bh * SEQ + nseq) * 64 + d;
#pragma unroll
        for (int r = 0; r < 4; r++)
          Kh[base + (size_t)r * 64] = f2bf(acc[fr][fc][r]);
      } else {                 // V: transposed [bh][d][SEQ]
        size_t base = ((size_t)bh * 64 + d) * SEQ + nseq;
        *reinterpret_cast<ushort4*>(&Vth[base]) =
            make_ushort4(f2bf(acc[fr][fc][0]), f2bf(acc[fr][fc][1]),
                         f2bf(acc[fr][fc][2]), f2bf(acc[fr][fc][3]));
      }
    }
  }
}

// ---------------- out-projection GEMM (plain bf16, dbuf + swizzle) ----------------
__global__ __launch_bounds__(256, 2) void k_gemm_out(
    const ushort_t* __restrict__ Ah, const ushort_t* __restrict__ Bth,
    float* __restrict__ C, const float* __restrict__ bias){
  __shared__ __align__(16) ushort_t Asm[2][GBM * GBK];
  __shared__ __align__(16) ushort_t Bsm[2][GBM * GBK];
  const int tid  = threadIdx.x;
  const int wave = tid >> 6, lane = tid & 63;
  const int mb = blockIdx.y * GBM, nb = blockIdx.x * GBN;
  const int wr = wave >> 1, wc = wave & 1;
  const int l15 = lane & 15, l4 = lane >> 4;
  const int rsub = lane >> 3;
  const int schunk = ((lane & 7) ^ rsub) * 8;
  f32x4 acc[4][4] = {};

  auto stage = [&](int buf, int kb){
    int k0 = kb * GBK;
#pragma unroll
    for (int i = 0; i < 4; i++){
      int row = (i * 4 + wave) * 8 + rsub;
      g2l16(Ah  + (size_t)(mb + row) * 1024 + k0 + schunk, &Asm[buf][(i * 4 + wave) * 512]);
      g2l16(Bth + (size_t)(nb + row) * 1024 + k0 + schunk, &Bsm[buf][(i * 4 + wave) * 512]);
    }
  };

  stage(0, 0);

  for (int kb = 0; kb < 16; kb++){
    const int cur = kb & 1;
    if (kb < 15){
      stage(cur ^ 1, kb + 1);
      asm volatile("s_waitcnt vmcnt(8)" ::: "memory");
    } else {
      asm volatile("s_waitcnt vmcnt(0)" ::: "memory");
    }
    __builtin_amdgcn_s_barrier();
    __builtin_amdgcn_s_setprio(1);
#pragma unroll
    for (int ks = 0; ks < 2; ks++){
      s8v af[4], bfr[4];
#pragma unroll
      for (int f = 0; f < 4; f++){
        int ch = (((ks * 4 + l4) ^ (l15 & 7)) << 3);
        af[f]  = *reinterpret_cast<const s8v*>(&Asm[cur][(wr * 64 + f * 16 + l15) * 64 + ch]);
        bfr[f] = *reinterpret_cast<const s8v*>(&Bsm[cur][(wc * 64 + f * 16 + l15) * 64 + ch]);
      }
#pragma unroll
      for (int fr = 0; fr < 4; fr++)
#pragma unroll
        for (int fc = 0; fc < 4; fc++)
          acc[fr][fc] = __builtin_amdgcn_mfma_f32_16x16x32_bf16(af[fr], bfr[fc], acc[fr][fc], 0, 0, 0);
    }
    __builtin_amdgcn_s_setprio(0);
    __builtin_amdgcn_s_barrier();
  }
#pragma unroll
  for (int fr = 0; fr < 4; fr++){
    int row = mb + wr * 64 + fr * 16 + l4 * 4;
#pragma unroll
    for (int fc = 0; fc < 4; fc++){
      int col = nb + wc * 64 + fc * 16 + l15;
      float bv = bias[col];
#pragma unroll
      for (int r = 0; r < 4; r++)
        C[(size_t)(row + r) * 1024 + col] = acc[fr][fc][r] + bv;
    }
  }
}

// ---------------- flash attention (QBLK=128, swapped QK^T, LDS-amortized) ----------------
// Grid 512 (XCD-remapped), 4 waves x 32 q-rows (2 fr groups of 16). KV tiles of 64.
// Each K/V fragment read from LDS feeds BOTH fr-groups' MFMAs (2x amortization).
// K and V double-buffered; stage(kt+1) issued at iter top -> in flight across the
// whole compute phase; single vmcnt(4) covers both. 2 barriers/iter.
// P: PhS[128 q][64], chunk-XOR swizzle (chunk ^= q&7); b64 writes 4-way-uniform
// (minimum for 8B/lane), b128 reads = one 16B chunk. P is wave-private (no barrier).
__global__ __launch_bounds__(256, 2) void k_flash(
    const ushort_t* __restrict__ Qh, const ushort_t* __restrict__ Kh,
    const ushort_t* __restrict__ Vth, ushort_t* __restrict__ Ah){
  __shared__ __align__(16) ushort_t KhS[2][64 * 64];
  __shared__ __align__(16) ushort_t VhS[2][64 * 64];
  __shared__ __align__(16) ushort_t PhS[128 * 64];
  const int lid = blockIdx.x;             // 0..511
  const int xcd = lid & 7, g = lid >> 3;  // 8 XCDs x 64 blocks
  const int bh = xcd * 4 + (g & 3);       // each XCD owns 4 heads (K/V L2-resident)
  const int qb = (g >> 2) * 128;
  const int tid = threadIdx.x, wave = tid >> 6, lane = tid & 63;
  const int l15 = lane & 15, l4 = lane >> 4;
  const int b = bh >> 4, h = bh & 15;
  const size_t hbase = (size_t)bh * SEQ * 64;
  const int rsub = lane >> 3;
  const int schunk = ((lane & 7) ^ rsub) * 8;

  // Q fragments (hi only), 32 q-rows per wave (2 fr groups of 16)
  s8v qhf[2][2];
#pragma unroll
  for (int fr = 0; fr < 2; fr++)
#pragma unroll
    for (int ks = 0; ks < 2; ks++){
      size_t off = hbase + (size_t)(qb + wave * 32 + fr * 16 + l15) * 64 + ks * 32 + l4 * 8;
      qhf[fr][ks] = *reinterpret_cast<const s8v*>(&Qh[off]);
    }

  f32x4 o[2][4] = {};
  float lsum[2] = {0.f, 0.f};

  auto stage = [&](int buf, int kt){
    int kvb = kt * 64;
#pragma unroll
    for (int i = 0; i < 2; i++){
      int row = (i * 4 + wave) * 8 + rsub;
      g2l16(Kh  + hbase + (size_t)(kvb + row) * 64 + schunk, &KhS[buf][(i * 4 + wave) * 512]);
      g2l16(Vth + ((size_t)bh * 64 + row) * SEQ + kvb + schunk, &VhS[buf][(i * 4 + wave) * 512]);
    }
  };

  stage(0, 0);

  for (int kt = 0; kt < 32; kt++){
    const int cur = kt & 1;
    if (kt < 31){
      stage(cur ^ 1, kt + 1);                          // next tile's 4 loads in flight
      asm volatile("s_waitcnt vmcnt(4)" ::: "memory"); // current tile's 4 landed
    } else {
      asm volatile("s_waitcnt vmcnt(0)" ::: "memory");
    }
    __builtin_amdgcn_s_barrier();

    // S^T = Kh Qh^T (swapped); each kh fragment feeds both fr groups
    f32x4 s[2][4] = {};
    __builtin_amdgcn_s_setprio(1);
#pragma unroll
    for (int ks = 0; ks < 2; ks++)
#pragma unroll
      for (int fc = 0; fc < 4; fc++){
        int rK = fc * 16 + l15;
        int ch = ((ks * 4 + l4) ^ (rK & 7)) << 3;
        s8v kh = *reinterpret_cast<const s8v*>(&KhS[cur][rK * 64 + ch]);
        s[0][fc] = __builtin_amdgcn_mfma_f32_16x16x32_bf16(kh, qhf[0][ks], s[0][fc], 0, 0, 0);
        s[1][fc] = __builtin_amdgcn_mfma_f32_16x16x32_bf16(kh, qhf[1][ks], s[1][fc], 0, 0, 0);
      }
    __builtin_amdgcn_s_setprio(0);

    // fixed-max softmax on S^T: lane holds q = wave*32 + fr*16 + l15,
    // kv = fc*16 + l4*4 + r. Pack to bf16, write chunk-XOR-swizzled b64.
#pragma unroll
    for (int fr = 0; fr < 2; fr++){
      int q = wave * 32 + fr * 16 + l15;
      int key = q & 7;
      int base = q * 64;
#pragma unroll
      for (int fc = 0; fc < 4; fc++){
        float p0 = __builtin_amdgcn_exp2f(s[fr][fc][0] - MFIX);
        float p1 = __builtin_amdgcn_exp2f(s[fr][fc][1] - MFIX);
        float p2 = __builtin_amdgcn_exp2f(s[fr][fc][2] - MFIX);
        float p3 = __builtin_amdgcn_exp2f(s[fr][fc][3] - MFIX);
        lsum[fr] += (p0 + p1) + (p2 + p3);
        uint2 w;
        w.x = cvt_pk_bf16(p0, p1);
        w.y = cvt_pk_bf16(p2, p3);
        *reinterpret_cast<uint2*>(
            &PhS[base + (((2 * fc + (l4 >> 1)) ^ key) << 3) + ((l4 & 1) << 2)]) = w;
      }
    }

    // O += P V ; each vh fragment feeds both fr groups
    __builtin_amdgcn_s_setprio(1);
#pragma unroll
    for (int c = 0; c < 2; c++){
      s8v pa[2];
#pragma unroll
      for (int fr = 0; fr < 2; fr++){
        int q = wave * 32 + fr * 16 + l15;
        pa[fr] = *reinterpret_cast<const s8v*>(&PhS[q * 64 + (((c * 4 + l4) ^ (q & 7)) << 3)]);
      }
#pragma unroll
      for (int fd = 0; fd < 4; fd++){
        int rV = fd * 16 + l15;
        int ch = ((c * 4 + l4) ^ (rV & 7)) << 3;
        s8v vh = *reinterpret_cast<const s8v*>(&VhS[cur][rV * 64 + ch]);
        o[0][fd] = __builtin_amdgcn_mfma_f32_16x16x32_bf16(pa[0], vh, o[0][fd], 0, 0, 0);
        o[1][fd] = __builtin_amdgcn_mfma_f32_16x16x32_bf16(pa[1], vh, o[1][fd], 0, 0, 0);
      }
    }
    __builtin_amdgcn_s_setprio(0);
    __builtin_amdgcn_s_barrier();   // all waves done reading cur buffers
  }

  // epilogue: lane holds lsum for q=l15 (per fr); reduce l4-groups, then
  // fetch per-output-row sums via lane shuffle. Output row q' = l4*4 + r.
#pragma unroll
  for (int fr = 0; fr < 2; fr++){
    lsum[fr] += __shfl_xor(lsum[fr], 16);
    lsum[fr] += __shfl_xor(lsum[fr], 32);
#pragma unroll
    for (int r = 0; r < 4; r++){
      float inv = 1.f / __shfl(lsum[fr], l4 * 4 + r);
      int n = qb + wave * 32 + fr * 16 + l4 * 4 + r;
      size_t rowbase = (size_t)(b * SEQ + n) * 1024 + h * 64;
#pragma unroll
      for (int fd = 0; fd < 4; fd++)
        Ah[rowbase + fd * 16 + l15] = f2bf(o[fr][fd][r] * inv);
    }
  }
}

// ---------------- host launch ----------------
extern "C" void kernel_launch(void* const* d_in, const int* in_sizes, int n_in,
                              void* d_out, int out_size, void* d_ws, size_t ws_size,
                              hipStream_t stream){
  const float* x     = (const float*)d_in[0];
  const float* w_qkv = (const float*)d_in[1];
  const float* w_out = (const float*)d_in[2];
  const float* b_out = (const float*)d_in[3];
  float* out = (float*)d_out;
  char* ws = (char*)d_ws;

  ushort_t* Xh    = (ushort_t*)(ws);                      //  8 MB
  ushort_t* Wqt_h = (ushort_t*)(ws + 8388608);            //  6 MB
  ushort_t* Wot_h = (ushort_t*)(ws + 14680064);           //  2 MB
  ushort_t* Qh    = (ushort_t*)(ws + 16777216);           //  8 MB
  ushort_t* Kh    = (ushort_t*)(ws + 25165824);           //  8 MB
  ushort_t* Vth   = (ushort_t*)(ws + 33554432);           //  8 MB
  ushort_t* Ah    = (ushort_t*)(ws + 41943040);           //  8 MB

  // 1. fused prep: x -> Xh; w_qkv -> Wqt_h (T); w_out -> Wot_h (T)
  k_prep<<<5120, 256, 0, stream>>>(x, w_qkv, w_out, Xh, Wqt_h, Wot_h);
  // 2. QKV projection with fused per-head epilogue
  k_gemm_qkv<<<dim3(24, 32), 256, 0, stream>>>(Xh, Wqt_h, Qh, Kh, Vth);
  // 3. attention -> Ah (bf16)
  k_flash<<<512, 256, 0, stream>>>(Qh, Kh, Vth, Ah);
  // 4. out = Ah @ Wot + b_out
  k_gemm_out<<<dim3(8, 32), 256, 0, stream>>>(Ah, Wot_h, out, b_out);
}